// Round 1
// baseline (2011.849 us; speedup 1.0000x reference)
//
#include <hip/hip_runtime.h>
#include <math.h>

#define HB 8
#define KD 64
#define VD 192
#define BT 2
#define TT 1536
#define CC 1536
#define HK (HB*KD)   // 512
#define HV (HB*VD)   // 1536

// ---------------- generic fp32 GEMM: C[M,N] = A[M,Kd] @ B[Kd,N] (+bias) ----------------
// 64x64 tile, 256 threads, 4x4 micro-tile, BK=16
template<bool WITH_BIAS>
__global__ __launch_bounds__(256) void gemm_f32(
    const float* __restrict__ A, const float* __restrict__ Bm,
    const float* __restrict__ bias, float* __restrict__ C,
    int M, int N, int Kd)
{
  __shared__ float As[16][68];  // [k][m] transposed for vector reads
  __shared__ float Bs[16][68];  // [k][n]
  const int t = threadIdx.x;
  const int tx = t & 15, ty = t >> 4;
  const int row0 = blockIdx.y * 64, col0 = blockIdx.x * 64;
  float acc[4][4] = {};
  for (int k0 = 0; k0 < Kd; k0 += 16) {
    {
      const int r = t >> 2, kk = (t & 3) * 4;
      float4 a4 = *(const float4*)&A[(size_t)(row0 + r) * Kd + k0 + kk];
      As[kk+0][r] = a4.x; As[kk+1][r] = a4.y; As[kk+2][r] = a4.z; As[kk+3][r] = a4.w;
      const int kb = t >> 4, c4 = (t & 15) * 4;
      *(float4*)&Bs[kb][c4] = *(const float4*)&Bm[(size_t)(k0 + kb) * N + col0 + c4];
    }
    __syncthreads();
    #pragma unroll
    for (int kk = 0; kk < 16; ++kk) {
      float4 a4 = *(const float4*)&As[kk][ty*4];
      float4 b4 = *(const float4*)&Bs[kk][tx*4];
      float av[4] = {a4.x, a4.y, a4.z, a4.w};
      float bv[4] = {b4.x, b4.y, b4.z, b4.w};
      #pragma unroll
      for (int i = 0; i < 4; ++i)
        #pragma unroll
        for (int j = 0; j < 4; ++j)
          acc[i][j] = fmaf(av[i], bv[j], acc[i][j]);
    }
    __syncthreads();
  }
  #pragma unroll
  for (int i = 0; i < 4; ++i) {
    const int r = row0 + ty*4 + i;
    #pragma unroll
    for (int j = 0; j < 4; ++j) {
      const int c = col0 + tx*4 + j;
      float val = acc[i][j];
      if (WITH_BIAS) val += bias[c];
      C[(size_t)r * N + c] = val;
    }
  }
}

// ---------------- r_k = positional_features @ Wrk ----------------
// pe[m, i<96]  = (cw[i] > |d|),  pe[m, 96+i] = sign(d) * (cw[i] > |d|)
// so r_k[m,c] = sum_{i: cw[i]>|d|} Wrk[i][c] + sign(d)*Wrk[96+i][c]
__global__ __launch_bounds__(256) void relk_kernel(
    const float* __restrict__ Wrk, float* __restrict__ rk)
{
  __shared__ float cw[96];
  const int t = threadIdx.x;
  if (t < 96) {
    double pr = exp(log((double)(TT + 1)) / 96.0);
    float prf = (float)pr;  // matches np .astype('float32') of exp(log(T+1)/96)
    cw[t] = (float)pow((double)prf, (double)(t + 1)) - 1.0f;
  }
  __syncthreads();
  const int m = blockIdx.x;            // 0 .. 2T-2
  const int d = m - (TT - 1);
  const float ad = fabsf((float)d);
  const float sg = (d > 0) ? 1.f : (d < 0 ? -1.f : 0.f);
  for (int c = t; c < HK; c += 256) {
    float acc = 0.f;
    for (int i = 0; i < 96; ++i) {
      if (cw[i] > ad) acc += Wrk[i*HK + c] + sg * Wrk[(96 + i)*HK + c];
    }
    rk[(size_t)m * HK + c] = acc;
  }
}

// ---------------- fused relative attention (flash-style) ----------------
// grid: B*H*(T/32) blocks, 256 threads. Q-tile=32, K-tile=32.
// logits[q,j] = (q*s+rwb) . k[j]  +  (q*s+rrb) . r_k[j - q + T-1]
__global__ __launch_bounds__(256) void attn_kernel(
    const float* __restrict__ q, const float* __restrict__ k,
    const float* __restrict__ v, const float* __restrict__ rk,
    const float* __restrict__ rwb, const float* __restrict__ rrb,
    float* __restrict__ aout)
{
  __shared__ float qw[32][65];
  __shared__ float qr[32][65];
  __shared__ float kt[32][65];
  __shared__ float rkb[63][65];
  __shared__ float S[32][33];

  const int t = threadIdx.x;
  const int bid = blockIdx.x;
  const int qt = bid % (TT/32);
  const int h  = (bid / (TT/32)) % HB;
  const int b  = bid / ((TT/32) * HB);
  const int q0 = qt * 32;

  // stage q*scale + biases
  for (int i = t; i < 32*64; i += 256) {
    const int r = i >> 6, c = i & 63;
    const float qs = q[((size_t)(b*TT) + q0 + r) * HK + h*KD + c] * 0.125f;
    qw[r][c] = qs + rwb[h*KD + c];
    qr[r][c] = qs + rrb[h*KD + c];
  }

  float acc[24];
  #pragma unroll
  for (int i = 0; i < 24; ++i) acc[i] = 0.f;
  float m_i = -1e30f, l_i = 0.f;

  const int r_s = t >> 3;   // row owned in softmax/PV phase (8 lanes/row, same wave)
  const int vsl = t & 7;    // v-column slice: 24 cols each

  for (int kt0 = 0; kt0 < TT; kt0 += 32) {
    __syncthreads();  // prev-iter PV reads of S done; safe to restage
    for (int i = t; i < 32*64; i += 256) {
      const int j = i >> 6, c = i & 63;
      kt[j][c] = k[((size_t)(b*TT) + kt0 + j) * HK + h*KD + c];
    }
    // r_k band: global row index m' = (kt0+j) - (q0+r) + T-1 = mbase + (j - r + 31)
    const int mbase = kt0 - q0 + (TT - 32);
    for (int i = t; i < 63*64; i += 256) {
      const int rr = i >> 6, c = i & 63;
      rkb[rr][c] = rk[(size_t)(mbase + rr) * HK + h*KD + c];
    }
    __syncthreads();
    // ---- logits: 2x2 micro-tile per thread ----
    {
      const int r0 = (t >> 4) * 2, j0 = (t & 15) * 2;
      const int base = j0 - r0 + 31;       // in [1,61]
      float s00=0.f, s01=0.f, s10=0.f, s11=0.f;
      #pragma unroll 8
      for (int c = 0; c < 64; ++c) {
        const float qw0 = qw[r0][c],  qw1 = qw[r0+1][c];
        const float qa0 = qr[r0][c],  qa1 = qr[r0+1][c];
        const float k0v = kt[j0][c],  k1v = kt[j0+1][c];
        const float rbm = rkb[base-1][c];
        const float rb0 = rkb[base][c];
        const float rbp = rkb[base+1][c];
        s00 = fmaf(qw0, k0v, fmaf(qa0, rb0, s00));
        s01 = fmaf(qw0, k1v, fmaf(qa0, rbp, s01));
        s10 = fmaf(qw1, k0v, fmaf(qa1, rbm, s10));
        s11 = fmaf(qw1, k1v, fmaf(qa1, rb0, s11));
      }
      S[r0][j0] = s00;   S[r0][j0+1] = s01;
      S[r0+1][j0] = s10; S[r0+1][j0+1] = s11;
    }
    __syncthreads();
    // ---- online softmax (intra-wave, 8 lanes per row) + PV ----
    {
      float lmax = -1e30f;
      #pragma unroll
      for (int i = 0; i < 4; ++i) lmax = fmaxf(lmax, S[r_s][vsl*4 + i]);
      #pragma unroll
      for (int s = 1; s < 8; s <<= 1) lmax = fmaxf(lmax, __shfl_xor(lmax, s, 64));
      const float m_new = fmaxf(m_i, lmax);
      const float corr = __expf(m_i - m_new);
      float lsum = 0.f;
      #pragma unroll
      for (int i = 0; i < 4; ++i) {
        const float p = __expf(S[r_s][vsl*4 + i] - m_new);
        S[r_s][vsl*4 + i] = p;     // same-wave RAW on LDS: safe without barrier
        lsum += p;
      }
      #pragma unroll
      for (int s = 1; s < 8; s <<= 1) lsum += __shfl_xor(lsum, s, 64);
      l_i = l_i * corr + lsum;
      m_i = m_new;
      #pragma unroll
      for (int i = 0; i < 24; ++i) acc[i] *= corr;
      const float* vbase = &v[((size_t)(b*TT) + kt0) * HV + h*VD + vsl*24];
      for (int j = 0; j < 32; ++j) {
        const float pj = S[r_s][j];
        const float4* vp = (const float4*)(vbase + (size_t)j * HV);
        #pragma unroll
        for (int i = 0; i < 6; ++i) {
          const float4 v4 = vp[i];
          acc[i*4+0] = fmaf(pj, v4.x, acc[i*4+0]);
          acc[i*4+1] = fmaf(pj, v4.y, acc[i*4+1]);
          acc[i*4+2] = fmaf(pj, v4.z, acc[i*4+2]);
          acc[i*4+3] = fmaf(pj, v4.w, acc[i*4+3]);
        }
      }
    }
  }
  const float inv = 1.0f / l_i;
  float* op = &aout[((size_t)(b*TT) + q0 + r_s) * HV + h*VD + vsl*24];
  #pragma unroll
  for (int i = 0; i < 24; ++i) op[i] = acc[i] * inv;
}

extern "C" void kernel_launch(void* const* d_in, const int* in_sizes, int n_in,
                              void* d_out, int out_size, void* d_ws, size_t ws_size,
                              hipStream_t stream)
{
  const float* X   = (const float*)d_in[0];
  const float* Wq  = (const float*)d_in[1];
  const float* Wk  = (const float*)d_in[2];
  const float* Wv  = (const float*)d_in[3];
  const float* Wrk = (const float*)d_in[4];
  const float* We  = (const float*)d_in[5];
  const float* be  = (const float*)d_in[6];
  const float* rwb = (const float*)d_in[7];
  const float* rrb = (const float*)d_in[8];
  float* out = (float*)d_out;

  float* ws   = (float*)d_ws;
  float* qb   = ws;                           // 3072*512
  float* kb   = qb + (size_t)3072*512;        // 3072*512
  float* vb   = kb + (size_t)3072*512;        // 3072*1536
  float* rk   = vb + (size_t)3072*1536;       // 3071*512
  float* ao   = rk + (size_t)3071*512;        // 3072*1536
  // total ~56.6 MB

  dim3 blk(256);
  gemm_f32<false><<<dim3(HK/64, (BT*TT)/64), blk, 0, stream>>>(X, Wq, nullptr, qb, BT*TT, HK, CC);
  gemm_f32<false><<<dim3(HK/64, (BT*TT)/64), blk, 0, stream>>>(X, Wk, nullptr, kb, BT*TT, HK, CC);
  gemm_f32<false><<<dim3(HV/64, (BT*TT)/64), blk, 0, stream>>>(X, Wv, nullptr, vb, BT*TT, HV, CC);
  relk_kernel<<<dim3(2*TT - 1), blk, 0, stream>>>(Wrk, rk);
  attn_kernel<<<dim3(BT*HB*(TT/32)), blk, 0, stream>>>(qb, kb, vb, rk, rwb, rrb, ao);
  gemm_f32<true><<<dim3(HV/64, (BT*TT)/64), blk, 0, stream>>>(ao, We, be, out, BT*TT, HV, HV);
}

// Round 2
// 945.807 us; speedup vs baseline: 2.1271x; 2.1271x over previous
//
#include <hip/hip_runtime.h>
#include <math.h>

#define HB 8
#define KD 64
#define VD 192
#define BT 2
#define TT 1536
#define CC 1536
#define HK (HB*KD)   // 512
#define HV (HB*VD)   // 1536

typedef float f32x4 __attribute__((ext_vector_type(4)));
typedef __bf16 bf16x8 __attribute__((ext_vector_type(8)));

static __device__ __forceinline__ ushort f2bf(float f) {
  union { float f; uint u; } v; v.f = f;
  uint r = (v.u + 0x7FFFu + ((v.u >> 16) & 1u)) >> 16;  // RNE
  return (ushort)r;
}
static __device__ __forceinline__ float bf2f(ushort u) {
  union { uint u; float f; } v; v.u = ((uint)u) << 16; return v.f;
}

static __device__ __forceinline__ f32x4 mfma16(const ushort* a, const ushort* b, f32x4 c) {
  bf16x8 av = *reinterpret_cast<const bf16x8*>(a);
  bf16x8 bv = *reinterpret_cast<const bf16x8*>(b);
  return __builtin_amdgcn_mfma_f32_16x16x32_bf16(av, bv, c, 0, 0, 0);
}

__device__ __forceinline__ void storeC(float* p, float v) { *p = v; }
__device__ __forceinline__ void storeC(ushort* p, float v) { *p = f2bf(v); }

// ---------------- fp32-math GEMM: C[M,N] = A[M,Kd] @ B[Kd,N] (+bias), OutT output ----------------
template<bool WITH_BIAS, typename OutT>
__global__ __launch_bounds__(256) void gemm_f32(
    const float* __restrict__ A, const float* __restrict__ Bm,
    const float* __restrict__ bias, OutT* __restrict__ C,
    int M, int N, int Kd)
{
  __shared__ float As[16][68];
  __shared__ float Bs[16][68];
  const int t = threadIdx.x;
  const int tx = t & 15, ty = t >> 4;
  const int row0 = blockIdx.y * 64, col0 = blockIdx.x * 64;
  float acc[4][4] = {};
  for (int k0 = 0; k0 < Kd; k0 += 16) {
    {
      const int r = t >> 2, kk = (t & 3) * 4;
      float4 a4 = *(const float4*)&A[(size_t)(row0 + r) * Kd + k0 + kk];
      As[kk+0][r] = a4.x; As[kk+1][r] = a4.y; As[kk+2][r] = a4.z; As[kk+3][r] = a4.w;
      const int kb = t >> 4, c4 = (t & 15) * 4;
      *(float4*)&Bs[kb][c4] = *(const float4*)&Bm[(size_t)(k0 + kb) * N + col0 + c4];
    }
    __syncthreads();
    #pragma unroll
    for (int kk = 0; kk < 16; ++kk) {
      float4 a4 = *(const float4*)&As[kk][ty*4];
      float4 b4 = *(const float4*)&Bs[kk][tx*4];
      float av[4] = {a4.x, a4.y, a4.z, a4.w};
      float bv[4] = {b4.x, b4.y, b4.z, b4.w};
      #pragma unroll
      for (int i = 0; i < 4; ++i)
        #pragma unroll
        for (int j = 0; j < 4; ++j)
          acc[i][j] = fmaf(av[i], bv[j], acc[i][j]);
    }
    __syncthreads();
  }
  #pragma unroll
  for (int i = 0; i < 4; ++i) {
    const int r = row0 + ty*4 + i;
    #pragma unroll
    for (int j = 0; j < 4; ++j) {
      const int c = col0 + tx*4 + j;
      float val = acc[i][j];
      if (WITH_BIAS) val += bias[c];
      storeC(&C[(size_t)r * N + c], val);
    }
  }
}

// ---------------- r_k = positional_features @ Wrk (bf16 out) ----------------
__global__ __launch_bounds__(256) void relk_kernel(
    const float* __restrict__ Wrk, ushort* __restrict__ rk)
{
  __shared__ float cw[96];
  const int t = threadIdx.x;
  if (t < 96) {
    double pr = exp(log((double)(TT + 1)) / 96.0);
    float prf = (float)pr;
    cw[t] = (float)pow((double)prf, (double)(t + 1)) - 1.0f;
  }
  __syncthreads();
  const int m = blockIdx.x;            // 0 .. 2T-2
  const int d = m - (TT - 1);
  const float ad = fabsf((float)d);
  const float sg = (d > 0) ? 1.f : (d < 0 ? -1.f : 0.f);
  for (int c = t; c < HK; c += 256) {
    float acc = 0.f;
    for (int i = 0; i < 96; ++i) {
      if (cw[i] > ad) acc += Wrk[i*HK + c] + sg * Wrk[(96 + i)*HK + c];
    }
    rk[(size_t)m * HK + c] = f2bf(acc);
  }
}

// ---------------- fused relative attention, bf16 MFMA ----------------
// grid: B*H*(T/32) blocks, 256 threads (4 waves). Q-tile=32, K-tile=32.
// S1 = (q*s+rwb) @ k^T via MFMA; S2 = (q*s+rrb) @ rkb^T via MFMA (63-row band);
// logits[q,j] = S1[q][j] + S2[q][j-q+31]; online softmax; PV via MFMA with vT.
__global__ __launch_bounds__(256) void attn_mfma(
    const ushort* __restrict__ q, const ushort* __restrict__ k,
    const ushort* __restrict__ v, const ushort* __restrict__ rk,
    const float* __restrict__ rwb, const float* __restrict__ rrb,
    float* __restrict__ aout)
{
  __shared__ ushort qw[32][72];   // pitch 144B: 16B aligned, conflict-free-ish
  __shared__ ushort qr[32][72];
  __shared__ ushort kt[32][72];
  __shared__ ushort rkb[64][72];  // row 63 zeroed (pad for MFMA)
  __shared__ ushort vT[192][40];  // transposed V: [vdim][key]
  __shared__ ushort Pl[32][40];   // probabilities bf16
  __shared__ float S1[32][33];
  __shared__ float S2[32][65];
  __shared__ float corrl[32], linv[32];

  const int t = threadIdx.x;
  const int wv = t >> 6, lane = t & 63;
  const int lrow = lane & 15, lk8 = lane >> 4;   // A/B frag: row/col = lrow, k0 = lk8*8
  const int bid = blockIdx.x;
  const int qt = bid % (TT/32);
  const int h  = (bid / (TT/32)) % HB;
  const int b  = bid / ((TT/32) * HB);
  const int q0 = qt * 32;

  // stage q*scale + biases (once)
  {
    const int r = t >> 3, c8 = t & 7;
    uint4 raw = *(const uint4*)&q[((size_t)(b*TT) + q0 + r) * HK + h*KD + c8*8];
    uint w[4] = {raw.x, raw.y, raw.z, raw.w};
    #pragma unroll
    for (int jj = 0; jj < 4; ++jj) {
      const int c = c8*8 + jj*2;
      const float f0 = bf2f((ushort)(w[jj] & 0xffff)) * 0.125f;
      const float f1 = bf2f((ushort)(w[jj] >> 16)) * 0.125f;
      qw[r][c]   = f2bf(f0 + rwb[h*KD + c]);
      qw[r][c+1] = f2bf(f1 + rwb[h*KD + c + 1]);
      qr[r][c]   = f2bf(f0 + rrb[h*KD + c]);
      qr[r][c+1] = f2bf(f1 + rrb[h*KD + c + 1]);
    }
    if (t < 64) rkb[63][t] = 0;
  }

  f32x4 acc[2][3];
  #pragma unroll
  for (int i = 0; i < 2; ++i)
    #pragma unroll
    for (int j = 0; j < 3; ++j) acc[i][j] = (f32x4){0.f, 0.f, 0.f, 0.f};
  float m_i = -1e30f, l_i = 0.f;
  const int r_s = t >> 3;   // softmax row (8 lanes/row, same wave)
  const int vsl = t & 7;

  for (int kt0 = 0; kt0 < TT; kt0 += 32) {
    __syncthreads();
    // ---- stage k tile ----
    { const int r = t >> 3, c8 = t & 7;
      *(uint4*)&kt[r][c8*8] = *(const uint4*)&k[((size_t)(b*TT) + kt0 + r) * HK + h*KD + c8*8]; }
    // ---- stage r_k band (63 rows) ----
    const int mbase = kt0 - q0 + (TT - 32);
    for (int i = t; i < 63*8; i += 256) {
      const int rr = i >> 3, c8 = i & 7;
      *(uint4*)&rkb[rr][c8*8] = *(const uint4*)&rk[(size_t)(mbase + rr) * HK + h*KD + c8*8];
    }
    // ---- stage vT (transposed) ----
    for (int i = t; i < 96*32; i += 256) {
      const int vd2 = i % 96, key = i / 96;
      uint pr = *(const uint*)&v[((size_t)(b*TT) + kt0 + key) * HV + h*VD + vd2*2];
      vT[vd2*2][key]   = (ushort)(pr & 0xffff);
      vT[vd2*2+1][key] = (ushort)(pr >> 16);
    }
    __syncthreads();
    // ---- S1 = qw @ kt^T : 4 waves x one 16x16 quadrant ----
    {
      const int rt = wv >> 1, ct = wv & 1;
      f32x4 c0 = (f32x4){0.f, 0.f, 0.f, 0.f};
      c0 = mfma16(&qw[rt*16 + lrow][lk8*8],      &kt[ct*16 + lrow][lk8*8],      c0);
      c0 = mfma16(&qw[rt*16 + lrow][32 + lk8*8], &kt[ct*16 + lrow][32 + lk8*8], c0);
      #pragma unroll
      for (int r = 0; r < 4; ++r) S1[rt*16 + lk8*4 + r][ct*16 + lrow] = c0[r];
    }
    // ---- S2 = qr @ rkb^T : 8 tiles (2x4), 2 per wave ----
    #pragma unroll
    for (int s2 = 0; s2 < 2; ++s2) {
      const int idx = wv*2 + s2;
      const int rt = idx >> 2, ct = idx & 3;
      f32x4 c0 = (f32x4){0.f, 0.f, 0.f, 0.f};
      c0 = mfma16(&qr[rt*16 + lrow][lk8*8],      &rkb[ct*16 + lrow][lk8*8],      c0);
      c0 = mfma16(&qr[rt*16 + lrow][32 + lk8*8], &rkb[ct*16 + lrow][32 + lk8*8], c0);
      #pragma unroll
      for (int r = 0; r < 4; ++r) S2[rt*16 + lk8*4 + r][ct*16 + lrow] = c0[r];
    }
    __syncthreads();
    // ---- online softmax with rel gather ----
    {
      float sv[4];
      #pragma unroll
      for (int i = 0; i < 4; ++i) {
        const int j = vsl*4 + i;
        sv[i] = S1[r_s][j] + S2[r_s][j - r_s + 31];
      }
      float lmax = fmaxf(fmaxf(sv[0], sv[1]), fmaxf(sv[2], sv[3]));
      #pragma unroll
      for (int s = 1; s < 8; s <<= 1) lmax = fmaxf(lmax, __shfl_xor(lmax, s, 64));
      const float m_new = fmaxf(m_i, lmax);
      const float corr = __expf(m_i - m_new);
      float lsum = 0.f;
      #pragma unroll
      for (int i = 0; i < 4; ++i) {
        const float p = __expf(sv[i] - m_new);
        Pl[r_s][vsl*4 + i] = f2bf(p);
        lsum += p;
      }
      #pragma unroll
      for (int s = 1; s < 8; s <<= 1) lsum += __shfl_xor(lsum, s, 64);
      l_i = l_i * corr + lsum;
      m_i = m_new;
      if (vsl == 0) corrl[r_s] = corr;
    }
    __syncthreads();
    // ---- PV: acc = acc*corr + P @ V ; wave wv owns v-cols [3wv*16, 3wv*16+48) ----
    {
      float cr[2][4];
      #pragma unroll
      for (int rt = 0; rt < 2; ++rt)
        #pragma unroll
        for (int r = 0; r < 4; ++r) cr[rt][r] = corrl[rt*16 + lk8*4 + r];
      #pragma unroll
      for (int rt = 0; rt < 2; ++rt) {
        const ushort* pa = &Pl[rt*16 + lrow][lk8*8];
        #pragma unroll
        for (int cc = 0; cc < 3; ++cc) {
          f32x4 a = acc[rt][cc];
          #pragma unroll
          for (int r = 0; r < 4; ++r) a[r] *= cr[rt][r];
          acc[rt][cc] = mfma16(pa, &vT[(3*wv + cc)*16 + lrow][lk8*8], a);
        }
      }
    }
  }
  if (vsl == 0) linv[r_s] = 1.0f / l_i;
  __syncthreads();
  #pragma unroll
  for (int rt = 0; rt < 2; ++rt) {
    #pragma unroll
    for (int cc = 0; cc < 3; ++cc) {
      const int colg = (3*wv + cc)*16 + lrow;
      #pragma unroll
      for (int r = 0; r < 4; ++r) {
        const int rowg = rt*16 + lk8*4 + r;
        aout[((size_t)(b*TT) + q0 + rowg) * HV + h*VD + colg] = acc[rt][cc][r] * linv[rowg];
      }
    }
  }
}

extern "C" void kernel_launch(void* const* d_in, const int* in_sizes, int n_in,
                              void* d_out, int out_size, void* d_ws, size_t ws_size,
                              hipStream_t stream)
{
  const float* X   = (const float*)d_in[0];
  const float* Wq  = (const float*)d_in[1];
  const float* Wk  = (const float*)d_in[2];
  const float* Wv  = (const float*)d_in[3];
  const float* Wrk = (const float*)d_in[4];
  const float* We  = (const float*)d_in[5];
  const float* be  = (const float*)d_in[6];
  const float* rwb = (const float*)d_in[7];
  const float* rrb = (const float*)d_in[8];
  float* out = (float*)d_out;

  char* ws = (char*)d_ws;
  ushort* qb = (ushort*)ws;                                   // 3072*512 bf16
  ushort* kb = qb + (size_t)3072*512;                         // 3072*512 bf16
  ushort* vb = kb + (size_t)3072*512;                         // 3072*1536 bf16
  ushort* rk = vb + (size_t)3072*1536;                        // 3071*512 bf16
  float*  ao = (float*)(rk + (size_t)3072*512);               // 3072*1536 f32

  dim3 blk(256);
  gemm_f32<false, ushort><<<dim3(HK/64, (BT*TT)/64), blk, 0, stream>>>(X, Wq, nullptr, qb, BT*TT, HK, CC);
  gemm_f32<false, ushort><<<dim3(HK/64, (BT*TT)/64), blk, 0, stream>>>(X, Wk, nullptr, kb, BT*TT, HK, CC);
  gemm_f32<false, ushort><<<dim3(HV/64, (BT*TT)/64), blk, 0, stream>>>(X, Wv, nullptr, vb, BT*TT, HV, CC);
  relk_kernel<<<dim3(2*TT - 1), blk, 0, stream>>>(Wrk, rk);
  attn_mfma<<<dim3(BT*HB*(TT/32)), blk, 0, stream>>>(qb, kb, vb, rk, rwb, rrb, ao);
  gemm_f32<true, float><<<dim3(HV/64, (BT*TT)/64), blk, 0, stream>>>(ao, We, be, out, BT*TT, HV, HV);
}

// Round 3
// 442.147 us; speedup vs baseline: 4.5502x; 2.1391x over previous
//
#include <hip/hip_runtime.h>
#include <math.h>

#define HB 8
#define KD 64
#define VD 192
#define BT 2
#define TT 1536
#define CC 1536
#define HK (HB*KD)   // 512
#define HV (HB*VD)   // 1536

typedef float f32x4 __attribute__((ext_vector_type(4)));
typedef __bf16 bf16x8 __attribute__((ext_vector_type(8)));

static __device__ __forceinline__ ushort f2bf(float f) {
  union { float f; uint u; } v; v.f = f;
  uint r = (v.u + 0x7FFFu + ((v.u >> 16) & 1u)) >> 16;  // RNE
  return (ushort)r;
}
static __device__ __forceinline__ float bf2f(ushort u) {
  union { uint u; float f; } v; v.u = ((uint)u) << 16; return v.f;
}

static __device__ __forceinline__ f32x4 mfma16(const ushort* a, const ushort* b, f32x4 c) {
  bf16x8 av = *reinterpret_cast<const bf16x8*>(a);
  bf16x8 bv = *reinterpret_cast<const bf16x8*>(b);
  return __builtin_amdgcn_mfma_f32_16x16x32_bf16(av, bv, c, 0, 0, 0);
}

static __device__ __forceinline__ void gload_lds16(const ushort* g, ushort* l) {
  __builtin_amdgcn_global_load_lds(
      (const __attribute__((address_space(1))) unsigned int*)g,
      (__attribute__((address_space(3))) unsigned int*)l, 16, 0, 0);
}

__device__ __forceinline__ void storeC(float* p, float v) { *p = v; }
__device__ __forceinline__ void storeC(ushort* p, float v) { *p = f2bf(v); }

// ---------------- cast fp32 -> bf16 (vectorized) ----------------
__global__ __launch_bounds__(256) void cast_bf16(
    const float* __restrict__ in, ushort* __restrict__ out, int n4)
{
  for (int i = blockIdx.x*blockDim.x + threadIdx.x; i < n4; i += gridDim.x*blockDim.x) {
    float4 v = ((const float4*)in)[i];
    ushort4 o; o.x = f2bf(v.x); o.y = f2bf(v.y); o.z = f2bf(v.z); o.w = f2bf(v.w);
    ((ushort4*)out)[i] = o;
  }
}

// ---------------- transpose + cast: in[R][C] fp32 -> out[C][R] bf16 ----------------
__global__ void tcast(const float* __restrict__ in, ushort* __restrict__ out, int R, int C)
{
  __shared__ float tile[32][33];
  const int bx = blockIdx.x * 32;  // col base of in
  const int by = blockIdx.y * 32;  // row base of in
  const int tx = threadIdx.x, ty = threadIdx.y;  // (32,8)
  #pragma unroll
  for (int i = 0; i < 4; ++i)
    tile[ty + i*8][tx] = in[(size_t)(by + ty + i*8)*C + bx + tx];
  __syncthreads();
  #pragma unroll
  for (int i = 0; i < 4; ++i)
    out[(size_t)(bx + ty + i*8)*R + by + tx] = f2bf(tile[tx][ty + i*8]);
}

// ---------------- bf16 MFMA GEMM: C[M,N] = A[M,Kd] @ Bt[N,Kd]^T (+bias) ----------------
// 128x128 tile, BK=64, 256 threads (4 waves, each 64x64 out), global_load_lds staging,
// XOR swizzle: LDS linear dest + inverse-swizzled global src + swizzled ds_read (rule 21).
template<bool WITH_BIAS, typename OutT>
__global__ __launch_bounds__(256) void gemm_bf16(
    const ushort* __restrict__ A, const ushort* __restrict__ Bt,
    const float* __restrict__ bias, OutT* __restrict__ C,
    int M, int N, int Kd)
{
  __shared__ __align__(16) ushort As[128*64];
  __shared__ __align__(16) ushort Bs[128*64];
  const int t = threadIdx.x;
  const int w = t >> 6, lane = t & 63;
  const int lrow = lane & 15, lk8 = lane >> 4;
  const int row0 = blockIdx.y * 128, col0 = blockIdx.x * 128;
  const int wr = (w >> 1) * 64, wc = (w & 1) * 64;

  f32x4 acc[4][4];
  #pragma unroll
  for (int m = 0; m < 4; ++m)
    #pragma unroll
    for (int n = 0; n < 4; ++n) acc[m][n] = (f32x4){0.f,0.f,0.f,0.f};

  for (int k0 = 0; k0 < Kd; k0 += 64) {
    __syncthreads();
    // stage A,B tiles: 1024 chunks of 16B each; chunk c=(r,cp), src chunk col = cp^(r&7)
    #pragma unroll
    for (int j = 0; j < 4; ++j) {
      const int c = (w*4 + j)*64 + lane;
      const int r = c >> 3, cp = c & 7;
      const int sc = cp ^ (r & 7);
      gload_lds16(A  + (size_t)(row0 + r)*Kd + k0 + sc*8, As + c*8);
      gload_lds16(Bt + (size_t)(col0 + r)*Kd + k0 + sc*8, Bs + c*8);
    }
    __syncthreads();
    bf16x8 af[4][2], bfv[4][2];
    #pragma unroll
    for (int m = 0; m < 4; ++m) {
      const int r = wr + m*16 + lrow;
      #pragma unroll
      for (int kh = 0; kh < 2; ++kh) {
        const int k8 = lk8 + kh*4;
        af[m][kh] = *(const bf16x8*)&As[r*64 + ((k8 ^ (r & 7)) << 3)];
      }
    }
    #pragma unroll
    for (int n = 0; n < 4; ++n) {
      const int r = wc + n*16 + lrow;
      #pragma unroll
      for (int kh = 0; kh < 2; ++kh) {
        const int k8 = lk8 + kh*4;
        bfv[n][kh] = *(const bf16x8*)&Bs[r*64 + ((k8 ^ (r & 7)) << 3)];
      }
    }
    #pragma unroll
    for (int m = 0; m < 4; ++m)
      #pragma unroll
      for (int n = 0; n < 4; ++n) {
        acc[m][n] = __builtin_amdgcn_mfma_f32_16x16x32_bf16(af[m][0], bfv[n][0], acc[m][n], 0, 0, 0);
        acc[m][n] = __builtin_amdgcn_mfma_f32_16x16x32_bf16(af[m][1], bfv[n][1], acc[m][n], 0, 0, 0);
      }
  }
  #pragma unroll
  for (int m = 0; m < 4; ++m)
    #pragma unroll
    for (int n = 0; n < 4; ++n) {
      const int cg = col0 + wc + n*16 + lrow;
      const float bb = WITH_BIAS ? bias[cg] : 0.f;
      #pragma unroll
      for (int r = 0; r < 4; ++r) {
        const int rg = row0 + wr + m*16 + lk8*4 + r;
        storeC(&C[(size_t)rg*N + cg], acc[m][n][r] + bb);
      }
    }
}

// ---------------- Wrk suffix sums: S1/S2[j][c] = sum_{i>=j} Wrk[i][c] / Wrk[96+i][c] ----------------
__global__ __launch_bounds__(256) void wrk_suffix(
    const float* __restrict__ Wrk, float* __restrict__ S1, float* __restrict__ S2)
{
  const int c = blockIdx.x*blockDim.x + threadIdx.x;  // 512 cols
  float a1 = 0.f, a2 = 0.f;
  S1[96*HK + c] = 0.f; S2[96*HK + c] = 0.f;
  for (int i = 95; i >= 0; --i) {
    a1 += Wrk[i*HK + c];
    a2 += Wrk[(96 + i)*HK + c];
    S1[i*HK + c] = a1; S2[i*HK + c] = a2;
  }
}

// ---------------- rk[m][c] = S1[i0][c] + sign(d)*S2[i0][c], bf16 ----------------
__global__ __launch_bounds__(256) void relk_fill(
    const float* __restrict__ S1, const float* __restrict__ S2, ushort* __restrict__ rk)
{
  __shared__ float cw[96];
  __shared__ int i0s;
  const int t = threadIdx.x;
  const int m = blockIdx.x;            // 0 .. 2T-2
  if (t < 96) {
    double pr = exp(log((double)(TT + 1)) / 96.0);
    float prf = (float)pr;
    cw[t] = (float)pow((double)prf, (double)(t + 1)) - 1.0f;
  }
  __syncthreads();
  const int d = m - (TT - 1);
  const float ad = fabsf((float)d);
  if (t == 0) {
    int i0 = 96;
    for (int i = 0; i < 96; ++i) if (cw[i] > ad) { i0 = i; break; }
    i0s = i0;
  }
  __syncthreads();
  const float sg = (d > 0) ? 1.f : (d < 0 ? -1.f : 0.f);
  const int i0 = i0s;
  for (int c = t; c < HK; c += 256)
    rk[(size_t)m * HK + c] = f2bf(S1[i0*HK + c] + sg * S2[i0*HK + c]);
}

// ---------------- fused relative attention, bf16 MFMA (bf16 out) ----------------
__global__ __launch_bounds__(256) void attn_mfma(
    const ushort* __restrict__ q, const ushort* __restrict__ k,
    const ushort* __restrict__ v, const ushort* __restrict__ rk,
    const float* __restrict__ rwb, const float* __restrict__ rrb,
    ushort* __restrict__ aout)
{
  __shared__ ushort qw[32][72];
  __shared__ ushort qr[32][72];
  __shared__ ushort kt[32][72];
  __shared__ ushort rkb[64][72];
  __shared__ ushort vT[192][40];
  __shared__ ushort Pl[32][40];
  __shared__ float S1[32][33];
  __shared__ float S2[32][65];
  __shared__ float corrl[32], linv[32];

  const int t = threadIdx.x;
  const int wv = t >> 6, lane = t & 63;
  const int lrow = lane & 15, lk8 = lane >> 4;
  const int bid = blockIdx.x;
  const int qt = bid % (TT/32);
  const int h  = (bid / (TT/32)) % HB;
  const int b  = bid / ((TT/32) * HB);
  const int q0 = qt * 32;

  {
    const int r = t >> 3, c8 = t & 7;
    uint4 raw = *(const uint4*)&q[((size_t)(b*TT) + q0 + r) * HK + h*KD + c8*8];
    uint wrd[4] = {raw.x, raw.y, raw.z, raw.w};
    #pragma unroll
    for (int jj = 0; jj < 4; ++jj) {
      const int c = c8*8 + jj*2;
      const float f0 = bf2f((ushort)(wrd[jj] & 0xffff)) * 0.125f;
      const float f1 = bf2f((ushort)(wrd[jj] >> 16)) * 0.125f;
      qw[r][c]   = f2bf(f0 + rwb[h*KD + c]);
      qw[r][c+1] = f2bf(f1 + rwb[h*KD + c + 1]);
      qr[r][c]   = f2bf(f0 + rrb[h*KD + c]);
      qr[r][c+1] = f2bf(f1 + rrb[h*KD + c + 1]);
    }
    if (t < 64) rkb[63][t] = 0;
  }

  f32x4 acc[2][3];
  #pragma unroll
  for (int i = 0; i < 2; ++i)
    #pragma unroll
    for (int j = 0; j < 3; ++j) acc[i][j] = (f32x4){0.f, 0.f, 0.f, 0.f};
  float m_i = -1e30f, l_i = 0.f;
  const int r_s = t >> 3;
  const int vsl = t & 7;

  for (int kt0 = 0; kt0 < TT; kt0 += 32) {
    __syncthreads();
    { const int r = t >> 3, c8 = t & 7;
      *(uint4*)&kt[r][c8*8] = *(const uint4*)&k[((size_t)(b*TT) + kt0 + r) * HK + h*KD + c8*8]; }
    const int mbase = kt0 - q0 + (TT - 32);
    for (int i = t; i < 63*8; i += 256) {
      const int rr = i >> 3, c8 = i & 7;
      *(uint4*)&rkb[rr][c8*8] = *(const uint4*)&rk[(size_t)(mbase + rr) * HK + h*KD + c8*8];
    }
    for (int i = t; i < 96*32; i += 256) {
      const int vd2 = i % 96, key = i / 96;
      uint pr = *(const uint*)&v[((size_t)(b*TT) + kt0 + key) * HV + h*VD + vd2*2];
      vT[vd2*2][key]   = (ushort)(pr & 0xffff);
      vT[vd2*2+1][key] = (ushort)(pr >> 16);
    }
    __syncthreads();
    {
      const int rt = wv >> 1, ct = wv & 1;
      f32x4 c0 = (f32x4){0.f, 0.f, 0.f, 0.f};
      c0 = mfma16(&qw[rt*16 + lrow][lk8*8],      &kt[ct*16 + lrow][lk8*8],      c0);
      c0 = mfma16(&qw[rt*16 + lrow][32 + lk8*8], &kt[ct*16 + lrow][32 + lk8*8], c0);
      #pragma unroll
      for (int r = 0; r < 4; ++r) S1[rt*16 + lk8*4 + r][ct*16 + lrow] = c0[r];
    }
    #pragma unroll
    for (int s2 = 0; s2 < 2; ++s2) {
      const int idx = wv*2 + s2;
      const int rt = idx >> 2, ct = idx & 3;
      f32x4 c0 = (f32x4){0.f, 0.f, 0.f, 0.f};
      c0 = mfma16(&qr[rt*16 + lrow][lk8*8],      &rkb[ct*16 + lrow][lk8*8],      c0);
      c0 = mfma16(&qr[rt*16 + lrow][32 + lk8*8], &rkb[ct*16 + lrow][32 + lk8*8], c0);
      #pragma unroll
      for (int r = 0; r < 4; ++r) S2[rt*16 + lk8*4 + r][ct*16 + lrow] = c0[r];
    }
    __syncthreads();
    {
      float sv[4];
      #pragma unroll
      for (int i = 0; i < 4; ++i) {
        const int j = vsl*4 + i;
        sv[i] = S1[r_s][j] + S2[r_s][j - r_s + 31];
      }
      float lmax = fmaxf(fmaxf(sv[0], sv[1]), fmaxf(sv[2], sv[3]));
      #pragma unroll
      for (int s = 1; s < 8; s <<= 1) lmax = fmaxf(lmax, __shfl_xor(lmax, s, 64));
      const float m_new = fmaxf(m_i, lmax);
      const float corr = __expf(m_i - m_new);
      float lsum = 0.f;
      #pragma unroll
      for (int i = 0; i < 4; ++i) {
        const float p = __expf(sv[i] - m_new);
        Pl[r_s][vsl*4 + i] = f2bf(p);
        lsum += p;
      }
      #pragma unroll
      for (int s = 1; s < 8; s <<= 1) lsum += __shfl_xor(lsum, s, 64);
      l_i = l_i * corr + lsum;
      m_i = m_new;
      if (vsl == 0) corrl[r_s] = corr;
    }
    __syncthreads();
    {
      float cr[2][4];
      #pragma unroll
      for (int rt = 0; rt < 2; ++rt)
        #pragma unroll
        for (int r = 0; r < 4; ++r) cr[rt][r] = corrl[rt*16 + lk8*4 + r];
      #pragma unroll
      for (int rt = 0; rt < 2; ++rt) {
        const ushort* pa = &Pl[rt*16 + lrow][lk8*8];
        #pragma unroll
        for (int cc = 0; cc < 3; ++cc) {
          f32x4 a = acc[rt][cc];
          #pragma unroll
          for (int r = 0; r < 4; ++r) a[r] *= cr[rt][r];
          acc[rt][cc] = mfma16(pa, &vT[(3*wv + cc)*16 + lrow][lk8*8], a);
        }
      }
    }
  }
  if (vsl == 0) linv[r_s] = 1.0f / l_i;
  __syncthreads();
  #pragma unroll
  for (int rt = 0; rt < 2; ++rt) {
    #pragma unroll
    for (int cc = 0; cc < 3; ++cc) {
      const int colg = (3*wv + cc)*16 + lrow;
      #pragma unroll
      for (int r = 0; r < 4; ++r) {
        const int rowg = rt*16 + lk8*4 + r;
        aout[((size_t)(b*TT) + q0 + rowg) * HV + h*VD + colg] = f2bf(acc[rt][cc][r] * linv[rowg]);
      }
    }
  }
}

extern "C" void kernel_launch(void* const* d_in, const int* in_sizes, int n_in,
                              void* d_out, int out_size, void* d_ws, size_t ws_size,
                              hipStream_t stream)
{
  const float* X   = (const float*)d_in[0];
  const float* Wq  = (const float*)d_in[1];
  const float* Wk  = (const float*)d_in[2];
  const float* Wv  = (const float*)d_in[3];
  const float* Wrk = (const float*)d_in[4];
  const float* We  = (const float*)d_in[5];
  const float* be  = (const float*)d_in[6];
  const float* rwb = (const float*)d_in[7];
  const float* rrb = (const float*)d_in[8];
  float* out = (float*)d_out;

  char* ws = (char*)d_ws;
  ushort* Xb  = (ushort*)ws;                         ws += (size_t)3072*1536*2;
  ushort* Wqt = (ushort*)ws;                         ws += (size_t)512*1536*2;
  ushort* Wkt = (ushort*)ws;                         ws += (size_t)512*1536*2;
  ushort* Wvt = (ushort*)ws;                         ws += (size_t)1536*1536*2;
  ushort* Wet = (ushort*)ws;                         ws += (size_t)1536*1536*2;
  float*  S1b = (float*)ws;                          ws += (size_t)97*512*4;
  float*  S2b = (float*)ws;                          ws += (size_t)97*512*4;
  ushort* qb  = (ushort*)ws;                         ws += (size_t)3072*512*2;
  ushort* kb  = (ushort*)ws;                         ws += (size_t)3072*512*2;
  ushort* vb  = (ushort*)ws;                         ws += (size_t)3072*1536*2;
  ushort* rk  = (ushort*)ws;                         ws += (size_t)3071*512*2;
  ushort* ao  = (ushort*)ws;                         // 3072*1536*2

  dim3 blk(256);
  cast_bf16<<<2048, blk, 0, stream>>>(X, Xb, (3072*1536)/4);
  tcast<<<dim3(512/32, 1536/32),  dim3(32,8), 0, stream>>>(Wq, Wqt, 1536, 512);
  tcast<<<dim3(512/32, 1536/32),  dim3(32,8), 0, stream>>>(Wk, Wkt, 1536, 512);
  tcast<<<dim3(1536/32, 1536/32), dim3(32,8), 0, stream>>>(Wv, Wvt, 1536, 1536);
  tcast<<<dim3(1536/32, 1536/32), dim3(32,8), 0, stream>>>(We, Wet, 1536, 1536);
  wrk_suffix<<<2, blk, 0, stream>>>(Wrk, S1b, S2b);
  relk_fill<<<dim3(2*TT - 1), blk, 0, stream>>>(S1b, S2b, rk);
  gemm_bf16<false, ushort><<<dim3(4, 24),  blk, 0, stream>>>(Xb, Wqt, nullptr, qb, 3072, 512, 1536);
  gemm_bf16<false, ushort><<<dim3(4, 24),  blk, 0, stream>>>(Xb, Wkt, nullptr, kb, 3072, 512, 1536);
  gemm_bf16<false, ushort><<<dim3(12, 24), blk, 0, stream>>>(Xb, Wvt, nullptr, vb, 3072, 1536, 1536);
  attn_mfma<<<dim3(BT*HB*(TT/32)), blk, 0, stream>>>(qb, kb, vb, rk, rwb, rrb, ao);
  gemm_bf16<true, float><<<dim3(12, 24),  blk, 0, stream>>>(ao, Wet, be, out, 3072, 1536, 1536);
}

// Round 4
// 261.456 us; speedup vs baseline: 7.6948x; 1.6911x over previous
//
#include <hip/hip_runtime.h>
#include <math.h>

#define HB 8
#define KD 64
#define VD 192
#define BT 2
#define TT 1536
#define CC 1536
#define HK (HB*KD)   // 512
#define HV (HB*VD)   // 1536
#define QKVP 2560    // fused qkv row pitch: q[0:512) k[512:1024) v[1024:2560)

typedef float f32x4 __attribute__((ext_vector_type(4)));
typedef __bf16 bf16x8 __attribute__((ext_vector_type(8)));

static __device__ __forceinline__ ushort f2bf(float f) {
  union { float f; uint u; } v; v.f = f;
  uint r = (v.u + 0x7FFFu + ((v.u >> 16) & 1u)) >> 16;  // RNE
  return (ushort)r;
}
static __device__ __forceinline__ float bf2f(ushort u) {
  union { uint u; float f; } v; v.u = ((uint)u) << 16; return v.f;
}

static __device__ __forceinline__ f32x4 mfma16(const ushort* a, const ushort* b, f32x4 c) {
  bf16x8 av = *reinterpret_cast<const bf16x8*>(a);
  bf16x8 bv = *reinterpret_cast<const bf16x8*>(b);
  return __builtin_amdgcn_mfma_f32_16x16x32_bf16(av, bv, c, 0, 0, 0);
}

static __device__ __forceinline__ void gload_lds16(const ushort* g, ushort* l) {
  __builtin_amdgcn_global_load_lds(
      (const __attribute__((address_space(1))) unsigned int*)g,
      (__attribute__((address_space(3))) unsigned int*)l, 16, 0, 0);
}

__device__ __forceinline__ void storeC(float* p, float v) { *p = v; }
__device__ __forceinline__ void storeC(ushort* p, float v) { *p = f2bf(v); }

// ---------------- cast fp32 -> bf16 (vectorized) ----------------
__global__ __launch_bounds__(256) void cast_bf16(
    const float* __restrict__ in, ushort* __restrict__ out, int n4)
{
  for (int i = blockIdx.x*blockDim.x + threadIdx.x; i < n4; i += gridDim.x*blockDim.x) {
    float4 v = ((const float4*)in)[i];
    ushort4 o; o.x = f2bf(v.x); o.y = f2bf(v.y); o.z = f2bf(v.z); o.w = f2bf(v.w);
    ((ushort4*)out)[i] = o;
  }
}

// ---------------- transpose + cast + scale: in[R][C] fp32 -> out[C][R] bf16 ----------------
__global__ void tcast(const float* __restrict__ in, ushort* __restrict__ out, int R, int C, float scale)
{
  __shared__ float tile[32][33];
  const int bx = blockIdx.x * 32;
  const int by = blockIdx.y * 32;
  const int tx = threadIdx.x, ty = threadIdx.y;  // (32,8)
  #pragma unroll
  for (int i = 0; i < 4; ++i)
    tile[ty + i*8][tx] = in[(size_t)(by + ty + i*8)*C + bx + tx];
  __syncthreads();
  #pragma unroll
  for (int i = 0; i < 4; ++i)
    out[(size_t)(bx + ty + i*8)*R + by + tx] = f2bf(tile[tx][ty + i*8] * scale);
}

// ---------------- bf16 MFMA GEMM: C[M,N] = A[M,Kd] @ Bt[N,Kd]^T (+bias) ----------------
template<bool WITH_BIAS, typename OutT>
__global__ __launch_bounds__(256) void gemm_bf16(
    const ushort* __restrict__ A, const ushort* __restrict__ Bt,
    const float* __restrict__ bias, OutT* __restrict__ C,
    int M, int N, int Kd)
{
  __shared__ __align__(16) ushort As[128*64];
  __shared__ __align__(16) ushort Bs[128*64];
  const int t = threadIdx.x;
  const int w = t >> 6, lane = t & 63;
  const int lrow = lane & 15, lk8 = lane >> 4;
  const int row0 = blockIdx.y * 128, col0 = blockIdx.x * 128;
  const int wr = (w >> 1) * 64, wc = (w & 1) * 64;

  f32x4 acc[4][4];
  #pragma unroll
  for (int m = 0; m < 4; ++m)
    #pragma unroll
    for (int n = 0; n < 4; ++n) acc[m][n] = (f32x4){0.f,0.f,0.f,0.f};

  for (int k0 = 0; k0 < Kd; k0 += 64) {
    __syncthreads();
    #pragma unroll
    for (int j = 0; j < 4; ++j) {
      const int c = (w*4 + j)*64 + lane;
      const int r = c >> 3, cp = c & 7;
      const int sc = cp ^ (r & 7);
      gload_lds16(A  + (size_t)(row0 + r)*Kd + k0 + sc*8, As + c*8);
      gload_lds16(Bt + (size_t)(col0 + r)*Kd + k0 + sc*8, Bs + c*8);
    }
    __syncthreads();
    bf16x8 af[4][2], bfv[4][2];
    #pragma unroll
    for (int m = 0; m < 4; ++m) {
      const int r = wr + m*16 + lrow;
      #pragma unroll
      for (int kh = 0; kh < 2; ++kh) {
        const int k8 = lk8 + kh*4;
        af[m][kh] = *(const bf16x8*)&As[r*64 + ((k8 ^ (r & 7)) << 3)];
      }
    }
    #pragma unroll
    for (int n = 0; n < 4; ++n) {
      const int r = wc + n*16 + lrow;
      #pragma unroll
      for (int kh = 0; kh < 2; ++kh) {
        const int k8 = lk8 + kh*4;
        bfv[n][kh] = *(const bf16x8*)&Bs[r*64 + ((k8 ^ (r & 7)) << 3)];
      }
    }
    #pragma unroll
    for (int m = 0; m < 4; ++m)
      #pragma unroll
      for (int n = 0; n < 4; ++n) {
        acc[m][n] = __builtin_amdgcn_mfma_f32_16x16x32_bf16(af[m][0], bfv[n][0], acc[m][n], 0, 0, 0);
        acc[m][n] = __builtin_amdgcn_mfma_f32_16x16x32_bf16(af[m][1], bfv[n][1], acc[m][n], 0, 0, 0);
      }
  }
  #pragma unroll
  for (int m = 0; m < 4; ++m)
    #pragma unroll
    for (int n = 0; n < 4; ++n) {
      const int cg = col0 + wc + n*16 + lrow;
      const float bb = WITH_BIAS ? bias[cg] : 0.f;
      #pragma unroll
      for (int r = 0; r < 4; ++r) {
        const int rg = row0 + wr + m*16 + lk8*4 + r;
        storeC(&C[(size_t)rg*N + cg], acc[m][n][r] + bb);
      }
    }
}

// ---------------- Wrk suffix sums ----------------
__global__ __launch_bounds__(256) void wrk_suffix(
    const float* __restrict__ Wrk, float* __restrict__ S1, float* __restrict__ S2)
{
  const int c = blockIdx.x*blockDim.x + threadIdx.x;
  float a1 = 0.f, a2 = 0.f;
  S1[96*HK + c] = 0.f; S2[96*HK + c] = 0.f;
  for (int i = 95; i >= 0; --i) {
    a1 += Wrk[i*HK + c];
    a2 += Wrk[(96 + i)*HK + c];
    S1[i*HK + c] = a1; S2[i*HK + c] = a2;
  }
}

// ---------------- rk[m][c] bf16 + c2[h][m] = rrb_h . rk[m] ----------------
__global__ __launch_bounds__(256) void relk_fill(
    const float* __restrict__ S1, const float* __restrict__ S2,
    const float* __restrict__ rrb, ushort* __restrict__ rk, float* __restrict__ c2g)
{
  __shared__ float cw[96];
  __shared__ float red[512];
  __shared__ int i0s;
  const int t = threadIdx.x;
  const int m = blockIdx.x;            // 0 .. 2T-2
  if (t < 96) {
    double pr = exp(log((double)(TT + 1)) / 96.0);
    float prf = (float)pr;
    cw[t] = (float)pow((double)prf, (double)(t + 1)) - 1.0f;
  }
  __syncthreads();
  const int d = m - (TT - 1);
  const float ad = fabsf((float)d);
  if (t == 0) {
    int i0 = 96;
    for (int i = 0; i < 96; ++i) if (cw[i] > ad) { i0 = i; break; }
    i0s = i0;
  }
  __syncthreads();
  const float sg = (d > 0) ? 1.f : (d < 0 ? -1.f : 0.f);
  const int i0 = i0s;
  for (int c = t; c < HK; c += 256) {
    const float val = S1[i0*HK + c] + sg * S2[i0*HK + c];
    const ushort vb = f2bf(val);
    rk[(size_t)m * HK + c] = vb;
    red[c] = bf2f(vb) * rrb[c];
  }
  __syncthreads();
  if (t < 8) {
    float s = 0.f;
    #pragma unroll 16
    for (int i = 0; i < 64; ++i) s += red[t*64 + i];
    c2g[(size_t)t*(2*TT - 1) + m] = s;
  }
}

// ---------------- c1[h][row] = rwb_h . k[row] ----------------
__global__ __launch_bounds__(256) void c1_kernel(
    const ushort* __restrict__ qkv, const float* __restrict__ rwb, float* __restrict__ c1g)
{
  const int idx = blockIdx.x*256 + threadIdx.x;  // 3072*8
  const int h = idx & 7, row = idx >> 3;
  const ushort* kr = &qkv[(size_t)row*QKVP + 512 + h*KD];
  float s = 0.f;
  #pragma unroll 16
  for (int c = 0; c < 64; ++c) s += bf2f(kr[c]) * rwb[h*KD + c];
  c1g[h*(BT*TT) + row] = s;
}

// ---------------- fused relative attention, bf16 MFMA ----------------
// logits[q][j] = qs_q.k_j + qs_q.rk_m + c1[j] + c2[m],  m = j - q + 31 (per tile)
__global__ __launch_bounds__(256) void attn_mfma(
    const ushort* __restrict__ qkv, const ushort* __restrict__ rk,
    const float* __restrict__ c1g, const float* __restrict__ c2g,
    ushort* __restrict__ aout)
{
  __shared__ ushort qs[32][72];
  __shared__ ushort kt[32][72];
  __shared__ ushort rkb[64][72];
  __shared__ ushort vT[192][40];
  __shared__ ushort Pl[32][40];
  __shared__ float S1[32][33];
  __shared__ float S2[32][65];
  __shared__ float c1s[32], c2s[64];
  __shared__ float corrl[32], linv[32];

  const int t = threadIdx.x;
  const int wv = t >> 6, lane = t & 63;
  const int lrow = lane & 15, lk8 = lane >> 4;
  const int bid = blockIdx.x;
  const int qt = bid % (TT/32);
  const int h  = (bid / (TT/32)) % HB;
  const int b  = bid / ((TT/32) * HB);
  const int q0 = qt * 32;

  // stage qs (pre-scaled by 0.125 via Wq tcast): raw uint4 copy
  {
    const int r = t >> 3, c8 = t & 7;
    *(uint4*)&qs[r][c8*8] = *(const uint4*)&qkv[((size_t)(b*TT) + q0 + r)*QKVP + h*KD + c8*8];
    if (t < 64) rkb[63][t] = 0;
  }

  f32x4 acc[2][3];
  #pragma unroll
  for (int i = 0; i < 2; ++i)
    #pragma unroll
    for (int j = 0; j < 3; ++j) acc[i][j] = (f32x4){0.f, 0.f, 0.f, 0.f};
  float m_i = -1e30f, l_i = 0.f;
  const int r_s = t >> 3;
  const int vsl = t & 7;

  // vT staging constants: lane = (key, half); halves write disjoint bank windows
  const int vkey = t & 31;
  const int vhf  = (t >> 5) & 1;
  const int vro  = vhf * 4;

  for (int kt0 = 0; kt0 < TT; kt0 += 32) {
    __syncthreads();
    // ---- stage k tile ----
    { const int r = t >> 3, c8 = t & 7;
      *(uint4*)&kt[r][c8*8] = *(const uint4*)&qkv[((size_t)(b*TT) + kt0 + r)*QKVP + 512 + h*KD + c8*8]; }
    // ---- stage r_k band ----
    const int mbase = kt0 - q0 + (TT - 32);
    for (int i = t; i < 63*8; i += 256) {
      const int rr = i >> 3, c8 = i & 7;
      *(uint4*)&rkb[rr][c8*8] = *(const uint4*)&rk[(size_t)(mbase + rr) * HK + h*KD + c8*8];
    }
    // ---- stage c1/c2 tiles ----
    if (t < 32) c1s[t] = c1g[h*(BT*TT) + b*TT + kt0 + t];
    else if (t >= 64 && t < 128) {
      const int m = t - 64;
      c2s[m] = (m < 63) ? c2g[(size_t)h*(2*TT - 1) + mbase + m] : 0.f;
    }
    // ---- stage vT: conflict-free transpose (see theory) ----
    {
      const ushort* vrow = &qkv[((size_t)(b*TT) + kt0 + vkey)*QKVP + 1024 + h*VD];
      #pragma unroll
      for (int rep = 0; rep < 3; ++rep) {
        const int vd0 = ((wv*2 + vhf)*3 + rep) * 8;
        uint4 raw = *(const uint4*)&vrow[vd0];
        uint p0 = vhf ? raw.z : raw.x;
        uint p1 = vhf ? raw.w : raw.y;
        uint p2 = vhf ? raw.x : raw.z;
        uint p3 = vhf ? raw.y : raw.w;
        vT[vd0 + vro + 0][vkey] = (ushort)(p0 & 0xffff);
        vT[vd0 + vro + 1][vkey] = (ushort)(p0 >> 16);
        vT[vd0 + vro + 2][vkey] = (ushort)(p1 & 0xffff);
        vT[vd0 + vro + 3][vkey] = (ushort)(p1 >> 16);
        vT[vd0 + (vro^4) + 0][vkey] = (ushort)(p2 & 0xffff);
        vT[vd0 + (vro^4) + 1][vkey] = (ushort)(p2 >> 16);
        vT[vd0 + (vro^4) + 2][vkey] = (ushort)(p3 & 0xffff);
        vT[vd0 + (vro^4) + 3][vkey] = (ushort)(p3 >> 16);
      }
    }
    __syncthreads();
    // ---- S1 = qs @ kt^T (+c1) : 4 waves x one 16x16 quadrant ----
    {
      const int rt = wv >> 1, ct = wv & 1;
      f32x4 c0 = (f32x4){0.f, 0.f, 0.f, 0.f};
      c0 = mfma16(&qs[rt*16 + lrow][lk8*8],      &kt[ct*16 + lrow][lk8*8],      c0);
      c0 = mfma16(&qs[rt*16 + lrow][32 + lk8*8], &kt[ct*16 + lrow][32 + lk8*8], c0);
      const float cadd = c1s[ct*16 + lrow];
      #pragma unroll
      for (int r = 0; r < 4; ++r) S1[rt*16 + lk8*4 + r][ct*16 + lrow] = c0[r] + cadd;
    }
    // ---- S2 = qs @ rkb^T (+c2) : 8 tiles, 2 per wave ----
    #pragma unroll
    for (int s2 = 0; s2 < 2; ++s2) {
      const int idx = wv*2 + s2;
      const int rt = idx >> 2, ct = idx & 3;
      f32x4 c0 = (f32x4){0.f, 0.f, 0.f, 0.f};
      c0 = mfma16(&qs[rt*16 + lrow][lk8*8],      &rkb[ct*16 + lrow][lk8*8],      c0);
      c0 = mfma16(&qs[rt*16 + lrow][32 + lk8*8], &rkb[ct*16 + lrow][32 + lk8*8], c0);
      const float cadd = c2s[ct*16 + lrow];
      #pragma unroll
      for (int r = 0; r < 4; ++r) S2[rt*16 + lk8*4 + r][ct*16 + lrow] = c0[r] + cadd;
    }
    __syncthreads();
    // ---- online softmax with rel gather ----
    {
      float sv[4];
      #pragma unroll
      for (int i = 0; i < 4; ++i) {
        const int j = vsl*4 + i;
        sv[i] = S1[r_s][j] + S2[r_s][j - r_s + 31];
      }
      float lmax = fmaxf(fmaxf(sv[0], sv[1]), fmaxf(sv[2], sv[3]));
      #pragma unroll
      for (int s = 1; s < 8; s <<= 1) lmax = fmaxf(lmax, __shfl_xor(lmax, s, 64));
      const float m_new = fmaxf(m_i, lmax);
      const float corr = __expf(m_i - m_new);
      float p0 = __expf(sv[0] - m_new), p1 = __expf(sv[1] - m_new);
      float p2 = __expf(sv[2] - m_new), p3 = __expf(sv[3] - m_new);
      *(uint*)&Pl[r_s][vsl*4]     = (uint)f2bf(p0) | ((uint)f2bf(p1) << 16);
      *(uint*)&Pl[r_s][vsl*4 + 2] = (uint)f2bf(p2) | ((uint)f2bf(p3) << 16);
      float lsum = p0 + p1 + p2 + p3;
      #pragma unroll
      for (int s = 1; s < 8; s <<= 1) lsum += __shfl_xor(lsum, s, 64);
      l_i = l_i * corr + lsum;
      m_i = m_new;
      if (vsl == 0) corrl[r_s] = corr;
    }
    __syncthreads();
    // ---- PV ----
    {
      float cr[2][4];
      #pragma unroll
      for (int rt = 0; rt < 2; ++rt)
        #pragma unroll
        for (int r = 0; r < 4; ++r) cr[rt][r] = corrl[rt*16 + lk8*4 + r];
      #pragma unroll
      for (int rt = 0; rt < 2; ++rt) {
        const ushort* pa = &Pl[rt*16 + lrow][lk8*8];
        #pragma unroll
        for (int cc = 0; cc < 3; ++cc) {
          f32x4 a = acc[rt][cc];
          #pragma unroll
          for (int r = 0; r < 4; ++r) a[r] *= cr[rt][r];
          acc[rt][cc] = mfma16(pa, &vT[(3*wv + cc)*16 + lrow][lk8*8], a);
        }
      }
    }
  }
  if (vsl == 0) linv[r_s] = 1.0f / l_i;
  __syncthreads();
  #pragma unroll
  for (int rt = 0; rt < 2; ++rt) {
    #pragma unroll
    for (int cc = 0; cc < 3; ++cc) {
      const int colg = (3*wv + cc)*16 + lrow;
      #pragma unroll
      for (int r = 0; r < 4; ++r) {
        const int rowg = rt*16 + lk8*4 + r;
        aout[((size_t)(b*TT) + q0 + rowg) * HV + h*VD + colg] = f2bf(acc[rt][cc][r] * linv[rowg]);
      }
    }
  }
}

extern "C" void kernel_launch(void* const* d_in, const int* in_sizes, int n_in,
                              void* d_out, int out_size, void* d_ws, size_t ws_size,
                              hipStream_t stream)
{
  const float* X   = (const float*)d_in[0];
  const float* Wq  = (const float*)d_in[1];
  const float* Wk  = (const float*)d_in[2];
  const float* Wv  = (const float*)d_in[3];
  const float* Wrk = (const float*)d_in[4];
  const float* We  = (const float*)d_in[5];
  const float* be  = (const float*)d_in[6];
  const float* rwb = (const float*)d_in[7];
  const float* rrb = (const float*)d_in[8];
  float* out = (float*)d_out;

  char* ws = (char*)d_ws;
  ushort* Xb    = (ushort*)ws;                       ws += (size_t)3072*1536*2;
  ushort* Wqkvt = (ushort*)ws;                       ws += (size_t)2560*1536*2;
  ushort* Wet   = (ushort*)ws;                       ws += (size_t)1536*1536*2;
  float*  S1b   = (float*)ws;                        ws += (size_t)97*512*4;
  float*  S2b   = (float*)ws;                        ws += (size_t)97*512*4;
  ushort* qkvb  = (ushort*)ws;                       ws += (size_t)3072*2560*2;
  ushort* rk    = (ushort*)ws;                       ws += (size_t)3071*512*2;
  float*  c1g   = (float*)ws;                        ws += (size_t)8*3072*4;
  float*  c2g   = (float*)ws;                        ws += (size_t)8*3071*4;
  ushort* ao    = (ushort*)ws;                       // 3072*1536*2

  dim3 blk(256);
  cast_bf16<<<2048, blk, 0, stream>>>(X, Xb, (3072*1536)/4);
  tcast<<<dim3(512/32, 1536/32),  dim3(32,8), 0, stream>>>(Wq, Wqkvt,                      1536, 512,  0.125f);
  tcast<<<dim3(512/32, 1536/32),  dim3(32,8), 0, stream>>>(Wk, Wqkvt + (size_t)512*1536,   1536, 512,  1.0f);
  tcast<<<dim3(1536/32, 1536/32), dim3(32,8), 0, stream>>>(Wv, Wqkvt + (size_t)1024*1536,  1536, 1536, 1.0f);
  tcast<<<dim3(1536/32, 1536/32), dim3(32,8), 0, stream>>>(We, Wet, 1536, 1536, 1.0f);
  wrk_suffix<<<2, blk, 0, stream>>>(Wrk, S1b, S2b);
  relk_fill<<<dim3(2*TT - 1), blk, 0, stream>>>(S1b, S2b, rrb, rk, c2g);
  gemm_bf16<false, ushort><<<dim3(20, 24), blk, 0, stream>>>(Xb, Wqkvt, nullptr, qkvb, 3072, QKVP, 1536);
  c1_kernel<<<96, blk, 0, stream>>>(qkvb, rwb, c1g);
  attn_mfma<<<dim3(BT*HB*(TT/32)), blk, 0, stream>>>(qkvb, rk, c1g, c2g, ao);
  gemm_bf16<true, float><<<dim3(12, 24), blk, 0, stream>>>(ao, Wet, be, out, 3072, 1536, 1536);
}

// Round 6
// 226.031 us; speedup vs baseline: 8.9007x; 1.1567x over previous
//
#include <hip/hip_runtime.h>
#include <math.h>

#define HB 8
#define KD 64
#define VD 192
#define BT 2
#define TT 1536
#define CC 1536
#define HK (HB*KD)   // 512
#define HV (HB*VD)   // 1536
#define QKVP 2560    // fused qkv row pitch: q[0:512) k[512:1024) v[1024:2560)

typedef float f32x4 __attribute__((ext_vector_type(4)));
typedef __bf16 bf16x8 __attribute__((ext_vector_type(8)));
typedef uint uint2v __attribute__((ext_vector_type(2)));

static __device__ __forceinline__ ushort f2bf(float f) {
  union { float f; uint u; } v; v.f = f;
  uint r = (v.u + 0x7FFFu + ((v.u >> 16) & 1u)) >> 16;  // RNE
  return (ushort)r;
}
static __device__ __forceinline__ float bf2f(ushort u) {
  union { uint u; float f; } v; v.u = ((uint)u) << 16; return v.f;
}

static __device__ __forceinline__ f32x4 mfma_bf(bf16x8 a, bf16x8 b, f32x4 c) {
  return __builtin_amdgcn_mfma_f32_16x16x32_bf16(a, b, c, 0, 0, 0);
}

static __device__ __forceinline__ void gload_lds16(const ushort* g, ushort* l) {
  __builtin_amdgcn_global_load_lds(
      (const __attribute__((address_space(1))) unsigned int*)g,
      (__attribute__((address_space(3))) unsigned int*)l, 16, 0, 0);
}

__device__ __forceinline__ void storeC(float* p, float v) { *p = v; }
__device__ __forceinline__ void storeC(ushort* p, float v) { *p = f2bf(v); }

// ---------------- cast fp32 -> bf16 (vectorized) ----------------
__global__ __launch_bounds__(256) void cast_bf16(
    const float* __restrict__ in, ushort* __restrict__ out, int n4)
{
  for (int i = blockIdx.x*blockDim.x + threadIdx.x; i < n4; i += gridDim.x*blockDim.x) {
    float4 v = ((const float4*)in)[i];
    ushort4 o; o.x = f2bf(v.x); o.y = f2bf(v.y); o.z = f2bf(v.z); o.w = f2bf(v.w);
    ((ushort4*)out)[i] = o;
  }
}

// ---------------- transpose + cast + scale: in[R][C] fp32 -> out[C][R] bf16 ----------------
__global__ void tcast(const float* __restrict__ in, ushort* __restrict__ out, int R, int C, float scale)
{
  __shared__ float tile[32][33];
  const int bx = blockIdx.x * 32;
  const int by = blockIdx.y * 32;
  const int tx = threadIdx.x, ty = threadIdx.y;  // (32,8)
  #pragma unroll
  for (int i = 0; i < 4; ++i)
    tile[ty + i*8][tx] = in[(size_t)(by + ty + i*8)*C + bx + tx];
  __syncthreads();
  #pragma unroll
  for (int i = 0; i < 4; ++i)
    out[(size_t)(bx + ty + i*8)*R + by + tx] = f2bf(tile[tx][ty + i*8] * scale);
}

// ---------------- bf16 transpose of V section: qkv[key][1024+vd] -> vTg[vd][key] ----------------
__global__ void vtrans(const ushort* __restrict__ in, ushort* __restrict__ out)
{
  __shared__ ushort tile[32][33];
  const int bx = blockIdx.x * 32;  // vd base
  const int by = blockIdx.y * 32;  // key base
  const int tx = threadIdx.x, ty = threadIdx.y;  // (32,8)
  #pragma unroll
  for (int i = 0; i < 4; ++i)
    tile[ty + i*8][tx] = in[(size_t)(by + ty + i*8)*QKVP + 1024 + bx + tx];
  __syncthreads();
  #pragma unroll
  for (int i = 0; i < 4; ++i)
    out[(size_t)(bx + ty + i*8)*(BT*TT) + by + tx] = tile[tx][ty + i*8];
}

// ---------------- bf16 MFMA GEMM: C[M,N] = A[M,Kd] @ Bt[N,Kd]^T (+bias) ----------------
template<bool WITH_BIAS, typename OutT>
__global__ __launch_bounds__(256) void gemm_bf16(
    const ushort* __restrict__ A, const ushort* __restrict__ Bt,
    const float* __restrict__ bias, OutT* __restrict__ C,
    int M, int N, int Kd)
{
  __shared__ __align__(16) ushort As[128*64];
  __shared__ __align__(16) ushort Bs[128*64];
  const int t = threadIdx.x;
  const int w = t >> 6, lane = t & 63;
  const int lrow = lane & 15, lk8 = lane >> 4;
  const int row0 = blockIdx.y * 128, col0 = blockIdx.x * 128;
  const int wr = (w >> 1) * 64, wc = (w & 1) * 64;

  f32x4 acc[4][4];
  #pragma unroll
  for (int m = 0; m < 4; ++m)
    #pragma unroll
    for (int n = 0; n < 4; ++n) acc[m][n] = (f32x4){0.f,0.f,0.f,0.f};

  for (int k0 = 0; k0 < Kd; k0 += 64) {
    __syncthreads();
    #pragma unroll
    for (int j = 0; j < 4; ++j) {
      const int c = (w*4 + j)*64 + lane;
      const int r = c >> 3, cp = c & 7;
      const int sc = cp ^ (r & 7);
      gload_lds16(A  + (size_t)(row0 + r)*Kd + k0 + sc*8, As + c*8);
      gload_lds16(Bt + (size_t)(col0 + r)*Kd + k0 + sc*8, Bs + c*8);
    }
    __syncthreads();
    bf16x8 af[4][2], bfv[4][2];
    #pragma unroll
    for (int m = 0; m < 4; ++m) {
      const int r = wr + m*16 + lrow;
      #pragma unroll
      for (int kh = 0; kh < 2; ++kh) {
        const int k8 = lk8 + kh*4;
        af[m][kh] = *(const bf16x8*)&As[r*64 + ((k8 ^ (r & 7)) << 3)];
      }
    }
    #pragma unroll
    for (int n = 0; n < 4; ++n) {
      const int r = wc + n*16 + lrow;
      #pragma unroll
      for (int kh = 0; kh < 2; ++kh) {
        const int k8 = lk8 + kh*4;
        bfv[n][kh] = *(const bf16x8*)&Bs[r*64 + ((k8 ^ (r & 7)) << 3)];
      }
    }
    #pragma unroll
    for (int m = 0; m < 4; ++m)
      #pragma unroll
      for (int n = 0; n < 4; ++n) {
        acc[m][n] = mfma_bf(af[m][0], bfv[n][0], acc[m][n]);
        acc[m][n] = mfma_bf(af[m][1], bfv[n][1], acc[m][n]);
      }
  }
  #pragma unroll
  for (int m = 0; m < 4; ++m)
    #pragma unroll
    for (int n = 0; n < 4; ++n) {
      const int cg = col0 + wc + n*16 + lrow;
      const float bb = WITH_BIAS ? bias[cg] : 0.f;
      #pragma unroll
      for (int r = 0; r < 4; ++r) {
        const int rg = row0 + wr + m*16 + lk8*4 + r;
        storeC(&C[(size_t)rg*N + cg], acc[m][n][r] + bb);
      }
    }
}

// ---------------- Wrk suffix sums ----------------
__global__ __launch_bounds__(256) void wrk_suffix(
    const float* __restrict__ Wrk, float* __restrict__ S1, float* __restrict__ S2)
{
  const int c = blockIdx.x*blockDim.x + threadIdx.x;
  float a1 = 0.f, a2 = 0.f;
  S1[96*HK + c] = 0.f; S2[96*HK + c] = 0.f;
  for (int i = 95; i >= 0; --i) {
    a1 += Wrk[i*HK + c];
    a2 += Wrk[(96 + i)*HK + c];
    S1[i*HK + c] = a1; S2[i*HK + c] = a2;
  }
}

// ---------------- rk[m][c] bf16 + c2[h][m] = rrb_h . rk[m] ----------------
__global__ __launch_bounds__(256) void relk_fill(
    const float* __restrict__ S1, const float* __restrict__ S2,
    const float* __restrict__ rrb, ushort* __restrict__ rk, float* __restrict__ c2g)
{
  __shared__ float cw[96];
  __shared__ float red[512];
  __shared__ int i0s;
  const int t = threadIdx.x;
  const int m = blockIdx.x;            // 0 .. 2T-2
  if (t < 96) {
    double pr = exp(log((double)(TT + 1)) / 96.0);
    float prf = (float)pr;
    cw[t] = (float)pow((double)prf, (double)(t + 1)) - 1.0f;
  }
  __syncthreads();
  const int d = m - (TT - 1);
  const float ad = fabsf((float)d);
  if (t == 0) {
    int i0 = 96;
    for (int i = 0; i < 96; ++i) if (cw[i] > ad) { i0 = i; break; }
    i0s = i0;
  }
  __syncthreads();
  const float sg = (d > 0) ? 1.f : (d < 0 ? -1.f : 0.f);
  const int i0 = i0s;
  for (int c = t; c < HK; c += 256) {
    const float val = S1[i0*HK + c] + sg * S2[i0*HK + c];
    const ushort vb = f2bf(val);
    rk[(size_t)m * HK + c] = vb;
    red[c] = bf2f(vb) * rrb[c];
  }
  __syncthreads();
  if (t < 8) {
    float s = 0.f;
    #pragma unroll 16
    for (int i = 0; i < 64; ++i) s += red[t*64 + i];
    c2g[(size_t)t*(2*TT - 1) + m] = s;
  }
}

// ---------------- c1[h][row] = rwb_h . k[row] ----------------
__global__ __launch_bounds__(256) void c1_kernel(
    const ushort* __restrict__ qkv, const float* __restrict__ rwb, float* __restrict__ c1g)
{
  const int idx = blockIdx.x*256 + threadIdx.x;  // 3072*8
  const int h = idx & 7, row = idx >> 3;
  const ushort* kr = &qkv[(size_t)row*QKVP + 512 + h*KD];
  float s = 0.f;
  #pragma unroll 16
  for (int c = 0; c < 64; ++c) s += bf2f(kr[c]) * rwb[h*KD + c];
  c1g[h*(BT*TT) + row] = s;
}

// ---------------- fused relative attention, bf16 MFMA, full DMA staging ----------------
__global__ __launch_bounds__(256) void attn_mfma(
    const ushort* __restrict__ qkv, const ushort* __restrict__ vTg,
    const ushort* __restrict__ rk,
    const float* __restrict__ c1g, const float* __restrict__ c2g,
    ushort* __restrict__ aout)
{
  __shared__ __align__(16) ushort ktL[32*64];    // k tile, XOR-chunk swizzled (4 KB)
  __shared__ __align__(16) ushort rkbL[64*64];   // rk band rows 0..62 + zero row 63 (8 KB)
  __shared__ __align__(16) ushort vTl[192*64];   // vT tile [vd 192][key 64], XOR swizzled (24 KB)
  __shared__ __align__(16) ushort Pl[32][40];    // probabilities bf16
  __shared__ __align__(16) float S1[32][33];
  __shared__ __align__(16) float S2[32][66];
  __shared__ float c1s[32], c2s[64];
  __shared__ float corrl[32], linv[32];

  const int t = threadIdx.x;
  const int wv = t >> 6, lane = t & 63;
  const int lrow = lane & 15, lk8 = lane >> 4;
  const int bid = blockIdx.x;
  const int qt = bid % (TT/32);
  const int h  = (bid / (TT/32)) % HB;
  const int b  = bid / ((TT/32) * HB);
  const int q0 = qt * 32;

  // ---- q A-fragments: loop-invariant, straight from global to registers ----
  bf16x8 af[2][2];
  #pragma unroll
  for (int rt = 0; rt < 2; ++rt)
    #pragma unroll
    for (int kh = 0; kh < 2; ++kh)
      af[rt][kh] = *(const bf16x8*)&qkv[((size_t)(b*TT) + q0 + rt*16 + lrow)*QKVP + h*KD + kh*32 + lk8*8];

  // zero rk-band pad row 63 (never written by DMA)
  if (t < 32) ((uint*)rkbL)[63*32 + t] = 0;

  // ---- per-thread DMA pointers ----
  // k tile: 256 chunks, 1/thread
  const int kc_r = t >> 3, kc_p = t & 7;
  const ushort* ksrc = qkv + (size_t)(b*TT + kc_r)*QKVP + 512 + h*KD + (kc_p ^ (kc_r & 7))*8;
  ushort* kdst = ktL + t*8;
  // rk band: 504 chunks, 2 rounds
  const ushort* rsrc[2]; ushort* rdst[2];
  #pragma unroll
  for (int W = 0; W < 2; ++W) {
    const int c = W*256 + t;
    const int rr = c >> 3, cp = c & 7;
    rsrc[W] = rk + (size_t)(TT - 32 - q0 + rr)*HK + h*KD + (cp ^ (rr & 7))*8;
    rdst[W] = rkbL + c*8;
  }
  const bool rval = t < 248;  // round-1 validity (c < 504)
  // vT tile: 1536 chunks, 6 rounds, staged every other iteration (64 keys)
  const ushort* vsrc[6]; ushort* vdst[6];
  #pragma unroll
  for (int W = 0; W < 6; ++W) {
    const int c = W*256 + t;
    const int vd = c >> 3, cpk = c & 7;
    vsrc[W] = vTg + (size_t)(h*VD + vd)*(BT*TT) + b*TT + (cpk ^ (vd & 7))*8;
    vdst[W] = vTl + c*8;
  }

  f32x4 acc[2][3];
  #pragma unroll
  for (int i = 0; i < 2; ++i)
    #pragma unroll
    for (int j = 0; j < 3; ++j) acc[i][j] = (f32x4){0.f, 0.f, 0.f, 0.f};
  float m_i = -1e30f, l_i = 0.f;
  const int r_s = t >> 3;
  const int vsl = t & 7;

  for (int kt0 = 0; kt0 < TT; kt0 += 32) {
    __syncthreads();
    // ---- issue DMA staging ----
    gload_lds16(ksrc, kdst);                 ksrc += 32*QKVP;
    gload_lds16(rsrc[0], rdst[0]);           rsrc[0] += 32*HK;
    if (rval) gload_lds16(rsrc[1], rdst[1]); rsrc[1] += 32*HK;
    if ((kt0 & 32) == 0) {
      #pragma unroll
      for (int W = 0; W < 6; ++W) { gload_lds16(vsrc[W], vdst[W]); vsrc[W] += 64; }
    }
    // ---- c1/c2 tiles ----
    const int mbase = kt0 - q0 + (TT - 32);
    if (t < 32) c1s[t] = c1g[h*(BT*TT) + b*TT + kt0 + t];
    else if (t >= 64 && t < 128) {
      const int m = t - 64;
      c2s[m] = (m < 63) ? c2g[(size_t)h*(2*TT - 1) + mbase + m] : 0.f;
    }
    asm volatile("s_waitcnt vmcnt(0)" ::: "memory");
    __syncthreads();  // all tiles resident
    // ---- S1 = qs @ k^T (+c1): 4 tiles, 1 per wave ----
    {
      const int rt = wv >> 1, ct = wv & 1;
      const int jk = ct*16 + lrow;
      bf16x8 b0 = *(const bf16x8*)&ktL[jk*64 + ((lk8 ^ (jk & 7)) << 3)];
      bf16x8 b1 = *(const bf16x8*)&ktL[jk*64 + (((lk8 + 4) ^ (jk & 7)) << 3)];
      f32x4 c0 = (f32x4){0.f, 0.f, 0.f, 0.f};
      c0 = mfma_bf(af[rt][0], b0, c0);
      c0 = mfma_bf(af[rt][1], b1, c0);
      const float cadd = c1s[jk];
      #pragma unroll
      for (int r = 0; r < 4; ++r) S1[rt*16 + lk8*4 + r][jk] = c0[r] + cadd;
    }
    // ---- S2 = qs @ rkb^T (+c2): 8 tiles, 2 per wave ----
    #pragma unroll
    for (int s2 = 0; s2 < 2; ++s2) {
      const int rt = wv >> 1, ct = (wv & 1)*2 + s2;
      const int j2 = ct*16 + lrow;
      bf16x8 b0 = *(const bf16x8*)&rkbL[j2*64 + ((lk8 ^ (j2 & 7)) << 3)];
      bf16x8 b1 = *(const bf16x8*)&rkbL[j2*64 + (((lk8 + 4) ^ (j2 & 7)) << 3)];
      f32x4 c0 = (f32x4){0.f, 0.f, 0.f, 0.f};
      c0 = mfma_bf(af[rt][0], b0, c0);
      c0 = mfma_bf(af[rt][1], b1, c0);
      const float cadd = c2s[j2];
      #pragma unroll
      for (int r = 0; r < 4; ++r) S2[rt*16 + lk8*4 + r][j2] = c0[r] + cadd;
    }
    __syncthreads();
    // ---- online softmax with rel gather ----
    {
      float sv[4];
      #pragma unroll
      for (int i = 0; i < 4; ++i) {
        const int j = vsl*4 + i;
        sv[i] = S1[r_s][j] + S2[r_s][j - r_s + 31];
      }
      float lmax = fmaxf(fmaxf(sv[0], sv[1]), fmaxf(sv[2], sv[3]));
      #pragma unroll
      for (int s = 1; s < 8; s <<= 1) lmax = fmaxf(lmax, __shfl_xor(lmax, s, 64));
      const float m_new = fmaxf(m_i, lmax);
      const float corr = __expf(m_i - m_new);
      const float p0 = __expf(sv[0] - m_new), p1 = __expf(sv[1] - m_new);
      const float p2 = __expf(sv[2] - m_new), p3 = __expf(sv[3] - m_new);
      uint2v pw;
      pw.x = (uint)f2bf(p0) | ((uint)f2bf(p1) << 16);
      pw.y = (uint)f2bf(p2) | ((uint)f2bf(p3) << 16);
      *(uint2v*)&Pl[r_s][vsl*4] = pw;
      float lsum = (p0 + p1) + (p2 + p3);
      #pragma unroll
      for (int s = 1; s < 8; s <<= 1) lsum += __shfl_xor(lsum, s, 64);
      l_i = l_i * corr + lsum;
      m_i = m_new;
      if (vsl == 0) corrl[r_s] = corr;
    }
    __syncthreads();
    // ---- PV: contiguous vT reads + MFMA ----
    {
      const int kh4 = ((kt0 >> 5) & 1) * 4;   // key half within the 64-key vT tile
      float cr[2][4];
      #pragma unroll
      for (int rt = 0; rt < 2; ++rt)
        #pragma unroll
        for (int r = 0; r < 4; ++r) cr[rt][r] = corrl[rt*16 + lk8*4 + r];
      #pragma unroll
      for (int rt = 0; rt < 2; ++rt) {
        const bf16x8 pa = *(const bf16x8*)&Pl[rt*16 + lrow][lk8*8];
        #pragma unroll
        for (int cc = 0; cc < 3; ++cc) {
          const int rv = (3*wv + cc)*16 + lrow;
          const bf16x8 bv = *(const bf16x8*)&vTl[rv*64 + (((kh4 + lk8) ^ (rv & 7)) << 3)];
          f32x4 a = acc[rt][cc];
          #pragma unroll
          for (int r = 0; r < 4; ++r) a[r] *= cr[rt][r];
          acc[rt][cc] = mfma_bf(pa, bv, a);
        }
      }
    }
  }
  if (vsl == 0) linv[r_s] = 1.0f / l_i;
  __syncthreads();
  #pragma unroll
  for (int rt = 0; rt < 2; ++rt) {
    #pragma unroll
    for (int cc = 0; cc < 3; ++cc) {
      const int colg = (3*wv + cc)*16 + lrow;
      #pragma unroll
      for (int r = 0; r < 4; ++r) {
        const int rowg = rt*16 + lk8*4 + r;
        aout[((size_t)(b*TT) + q0 + rowg) * HV + h*VD + colg] = f2bf(acc[rt][cc][r] * linv[rowg]);
      }
    }
  }
}

extern "C" void kernel_launch(void* const* d_in, const int* in_sizes, int n_in,
                              void* d_out, int out_size, void* d_ws, size_t ws_size,
                              hipStream_t stream)
{
  const float* X   = (const float*)d_in[0];
  const float* Wq  = (const float*)d_in[1];
  const float* Wk  = (const float*)d_in[2];
  const float* Wv  = (const float*)d_in[3];
  const float* Wrk = (const float*)d_in[4];
  const float* We  = (const float*)d_in[5];
  const float* be  = (const float*)d_in[6];
  const float* rwb = (const float*)d_in[7];
  const float* rrb = (const float*)d_in[8];
  float* out = (float*)d_out;

  char* ws = (char*)d_ws;
  ushort* Xb    = (ushort*)ws;                       ws += (size_t)3072*1536*2;
  ushort* Wqkvt = (ushort*)ws;                       ws += (size_t)2560*1536*2;
  ushort* Wet   = (ushort*)ws;                       ws += (size_t)1536*1536*2;
  float*  S1b   = (float*)ws;                        ws += (size_t)97*512*4;
  float*  S2b   = (float*)ws;                        ws += (size_t)97*512*4;
  ushort* qkvb  = (ushort*)ws;                       ws += (size_t)3072*2560*2;
  ushort* vTgb  = (ushort*)ws;                       ws += (size_t)1536*3072*2;
  ushort* rkb   = (ushort*)ws;                       ws += (size_t)3071*512*2;
  float*  c1g   = (float*)ws;                        ws += (size_t)8*3072*4;
  float*  c2g   = (float*)ws;                        ws += (size_t)8*3071*4;
  ushort* ao    = (ushort*)ws;                       // 3072*1536*2

  dim3 blk(256);
  cast_bf16<<<2048, blk, 0, stream>>>(X, Xb, (3072*1536)/4);
  tcast<<<dim3(512/32, 1536/32),  dim3(32,8), 0, stream>>>(Wq, Wqkvt,                      1536, 512,  0.125f);
  tcast<<<dim3(512/32, 1536/32),  dim3(32,8), 0, stream>>>(Wk, Wqkvt + (size_t)512*1536,   1536, 512,  1.0f);
  tcast<<<dim3(1536/32, 1536/32), dim3(32,8), 0, stream>>>(Wv, Wqkvt + (size_t)1024*1536,  1536, 1536, 1.0f);
  tcast<<<dim3(1536/32, 1536/32), dim3(32,8), 0, stream>>>(We, Wet, 1536, 1536, 1.0f);
  wrk_suffix<<<2, blk, 0, stream>>>(Wrk, S1b, S2b);
  relk_fill<<<dim3(2*TT - 1), blk, 0, stream>>>(S1b, S2b, rrb, rkb, c2g);
  gemm_bf16<false, ushort><<<dim3(20, 24), blk, 0, stream>>>(Xb, Wqkvt, nullptr, qkvb, 3072, QKVP, 1536);
  vtrans<<<dim3(1536/32, 3072/32), dim3(32,8), 0, stream>>>(qkvb, vTgb);
  c1_kernel<<<96, blk, 0, stream>>>(qkvb, rwb, c1g);
  attn_mfma<<<dim3(BT*HB*(TT/32)), blk, 0, stream>>>(qkvb, vTgb, rkb, c1g, c2g, ao);
  gemm_bf16<true, float><<<dim3(12, 24), blk, 0, stream>>>(ao, Wet, be, out, 3072, 1536, 1536);
}

// Round 7
// 224.126 us; speedup vs baseline: 8.9764x; 1.0085x over previous
//
#include <hip/hip_runtime.h>
#include <math.h>

#define HB 8
#define KD 64
#define VD 192
#define BT 2
#define TT 1536
#define CC 1536
#define HK (HB*KD)   // 512
#define HV (HB*VD)   // 1536
#define QKVP 2560    // fused qkv row pitch: q[0:512) k[512:1024) v[1024:2560)
#define LOG2E 1.44269504088896340736f

typedef float f32x4 __attribute__((ext_vector_type(4)));
typedef __bf16 bf16x8 __attribute__((ext_vector_type(8)));
typedef uint uint2v __attribute__((ext_vector_type(2)));

static __device__ __forceinline__ ushort f2bf(float f) {
  union { float f; uint u; } v; v.f = f;
  uint r = (v.u + 0x7FFFu + ((v.u >> 16) & 1u)) >> 16;  // RNE
  return (ushort)r;
}
static __device__ __forceinline__ float bf2f(ushort u) {
  union { uint u; float f; } v; v.u = ((uint)u) << 16; return v.f;
}

static __device__ __forceinline__ f32x4 mfma_bf(bf16x8 a, bf16x8 b, f32x4 c) {
  return __builtin_amdgcn_mfma_f32_16x16x32_bf16(a, b, c, 0, 0, 0);
}

static __device__ __forceinline__ void gload_lds16(const ushort* g, ushort* l) {
  __builtin_amdgcn_global_load_lds(
      (const __attribute__((address_space(1))) unsigned int*)g,
      (__attribute__((address_space(3))) unsigned int*)l, 16, 0, 0);
}

__device__ __forceinline__ void storeC(float* p, float v) { *p = v; }
__device__ __forceinline__ void storeC(ushort* p, float v) { *p = f2bf(v); }

// ---------------- cast fp32 -> bf16 (vectorized) ----------------
__global__ __launch_bounds__(256) void cast_bf16(
    const float* __restrict__ in, ushort* __restrict__ out, int n4)
{
  for (int i = blockIdx.x*blockDim.x + threadIdx.x; i < n4; i += gridDim.x*blockDim.x) {
    float4 v = ((const float4*)in)[i];
    ushort4 o; o.x = f2bf(v.x); o.y = f2bf(v.y); o.z = f2bf(v.z); o.w = f2bf(v.w);
    ((ushort4*)out)[i] = o;
  }
}

// ---------------- transpose + cast + scale: in[R][C] fp32 -> out[C][R] bf16 ----------------
__global__ void tcast(const float* __restrict__ in, ushort* __restrict__ out, int R, int C, float scale)
{
  __shared__ float tile[32][33];
  const int bx = blockIdx.x * 32;
  const int by = blockIdx.y * 32;
  const int tx = threadIdx.x, ty = threadIdx.y;  // (32,8)
  #pragma unroll
  for (int i = 0; i < 4; ++i)
    tile[ty + i*8][tx] = in[(size_t)(by + ty + i*8)*C + bx + tx];
  __syncthreads();
  #pragma unroll
  for (int i = 0; i < 4; ++i)
    out[(size_t)(bx + ty + i*8)*R + by + tx] = f2bf(tile[tx][ty + i*8] * scale);
}

// ---------------- bf16 transpose of V section: qkv[key][1024+vd] -> vTg[vd][key] ----------------
__global__ void vtrans(const ushort* __restrict__ in, ushort* __restrict__ out)
{
  __shared__ ushort tile[32][33];
  const int bx = blockIdx.x * 32;  // vd base
  const int by = blockIdx.y * 32;  // key base
  const int tx = threadIdx.x, ty = threadIdx.y;  // (32,8)
  #pragma unroll
  for (int i = 0; i < 4; ++i)
    tile[ty + i*8][tx] = in[(size_t)(by + ty + i*8)*QKVP + 1024 + bx + tx];
  __syncthreads();
  #pragma unroll
  for (int i = 0; i < 4; ++i)
    out[(size_t)(bx + ty + i*8)*(BT*TT) + by + tx] = tile[tx][ty + i*8];
}

// ---------------- bf16 MFMA GEMM: C[M,N] = A[M,Kd] @ Bt[N,Kd]^T (+bias) ----------------
template<bool WITH_BIAS, typename OutT>
__global__ __launch_bounds__(256) void gemm_bf16(
    const ushort* __restrict__ A, const ushort* __restrict__ Bt,
    const float* __restrict__ bias, OutT* __restrict__ C,
    int M, int N, int Kd)
{
  __shared__ __align__(16) ushort As[128*64];
  __shared__ __align__(16) ushort Bs[128*64];
  const int t = threadIdx.x;
  const int w = t >> 6, lane = t & 63;
  const int lrow = lane & 15, lk8 = lane >> 4;
  const int row0 = blockIdx.y * 128, col0 = blockIdx.x * 128;
  const int wr = (w >> 1) * 64, wc = (w & 1) * 64;

  f32x4 acc[4][4];
  #pragma unroll
  for (int m = 0; m < 4; ++m)
    #pragma unroll
    for (int n = 0; n < 4; ++n) acc[m][n] = (f32x4){0.f,0.f,0.f,0.f};

  for (int k0 = 0; k0 < Kd; k0 += 64) {
    __syncthreads();
    #pragma unroll
    for (int j = 0; j < 4; ++j) {
      const int c = (w*4 + j)*64 + lane;
      const int r = c >> 3, cp = c & 7;
      const int sc = cp ^ (r & 7);
      gload_lds16(A  + (size_t)(row0 + r)*Kd + k0 + sc*8, As + c*8);
      gload_lds16(Bt + (size_t)(col0 + r)*Kd + k0 + sc*8, Bs + c*8);
    }
    __syncthreads();
    bf16x8 af[4][2], bfv[4][2];
    #pragma unroll
    for (int m = 0; m < 4; ++m) {
      const int r = wr + m*16 + lrow;
      #pragma unroll
      for (int kh = 0; kh < 2; ++kh) {
        const int k8 = lk8 + kh*4;
        af[m][kh] = *(const bf16x8*)&As[r*64 + ((k8 ^ (r & 7)) << 3)];
      }
    }
    #pragma unroll
    for (int n = 0; n < 4; ++n) {
      const int r = wc + n*16 + lrow;
      #pragma unroll
      for (int kh = 0; kh < 2; ++kh) {
        const int k8 = lk8 + kh*4;
        bfv[n][kh] = *(const bf16x8*)&Bs[r*64 + ((k8 ^ (r & 7)) << 3)];
      }
    }
    #pragma unroll
    for (int m = 0; m < 4; ++m)
      #pragma unroll
      for (int n = 0; n < 4; ++n) {
        acc[m][n] = mfma_bf(af[m][0], bfv[n][0], acc[m][n]);
        acc[m][n] = mfma_bf(af[m][1], bfv[n][1], acc[m][n]);
      }
  }
  #pragma unroll
  for (int m = 0; m < 4; ++m)
    #pragma unroll
    for (int n = 0; n < 4; ++n) {
      const int cg = col0 + wc + n*16 + lrow;
      const float bb = WITH_BIAS ? bias[cg] : 0.f;
      #pragma unroll
      for (int r = 0; r < 4; ++r) {
        const int rg = row0 + wr + m*16 + lk8*4 + r;
        storeC(&C[(size_t)rg*N + cg], acc[m][n][r] + bb);
      }
    }
}

// ---------------- Wrk suffix sums ----------------
__global__ __launch_bounds__(256) void wrk_suffix(
    const float* __restrict__ Wrk, float* __restrict__ S1, float* __restrict__ S2)
{
  const int c = blockIdx.x*blockDim.x + threadIdx.x;
  float a1 = 0.f, a2 = 0.f;
  S1[96*HK + c] = 0.f; S2[96*HK + c] = 0.f;
  for (int i = 95; i >= 0; --i) {
    a1 += Wrk[i*HK + c];
    a2 += Wrk[(96 + i)*HK + c];
    S1[i*HK + c] = a1; S2[i*HK + c] = a2;
  }
}

// ---------------- rk[m][c] bf16 + c2[h][m] = (rrb_h . rk[m]) * log2e ----------------
__global__ __launch_bounds__(256) void relk_fill(
    const float* __restrict__ S1, const float* __restrict__ S2,
    const float* __restrict__ rrb, ushort* __restrict__ rk, float* __restrict__ c2g)
{
  __shared__ float cw[96];
  __shared__ float red[512];
  __shared__ int i0s;
  const int t = threadIdx.x;
  const int m = blockIdx.x;            // 0 .. 2T-2
  if (t < 96) {
    double pr = exp(log((double)(TT + 1)) / 96.0);
    float prf = (float)pr;
    cw[t] = (float)pow((double)prf, (double)(t + 1)) - 1.0f;
  }
  __syncthreads();
  const int d = m - (TT - 1);
  const float ad = fabsf((float)d);
  if (t == 0) {
    int i0 = 96;
    for (int i = 0; i < 96; ++i) if (cw[i] > ad) { i0 = i; break; }
    i0s = i0;
  }
  __syncthreads();
  const float sg = (d > 0) ? 1.f : (d < 0 ? -1.f : 0.f);
  const int i0 = i0s;
  for (int c = t; c < HK; c += 256) {
    const float val = S1[i0*HK + c] + sg * S2[i0*HK + c];
    const ushort vb = f2bf(val);
    rk[(size_t)m * HK + c] = vb;
    red[c] = bf2f(vb) * rrb[c];
  }
  __syncthreads();
  if (t < 8) {
    float s = 0.f;
    #pragma unroll 16
    for (int i = 0; i < 64; ++i) s += red[t*64 + i];
    c2g[(size_t)t*(2*TT - 1) + m] = s * LOG2E;
  }
}

// ---------------- c1[h][row] = (rwb_h . k[row]) * log2e ----------------
__global__ __launch_bounds__(256) void c1_kernel(
    const ushort* __restrict__ qkv, const float* __restrict__ rwb, float* __restrict__ c1g)
{
  const int idx = blockIdx.x*256 + threadIdx.x;  // 3072*8
  const int h = idx & 7, row = idx >> 3;
  const ushort* kr = &qkv[(size_t)row*QKVP + 512 + h*KD];
  float s = 0.f;
  #pragma unroll 16
  for (int c = 0; c < 64; ++c) s += bf2f(kr[c]) * rwb[h*KD + c];
  c1g[h*(BT*TT) + row] = s * LOG2E;
}

// ---------------- fused relative attention: pipelined DMA, defer-max, exp2 domain ----------------
__global__ __launch_bounds__(256) void attn_mfma(
    const ushort* __restrict__ qkv, const ushort* __restrict__ vTg,
    const ushort* __restrict__ rk,
    const float* __restrict__ c1g, const float* __restrict__ c2g,
    ushort* __restrict__ aout)
{
  __shared__ __align__(16) ushort ktL[32*64];    // k tile (4 KB)
  __shared__ __align__(16) ushort rkbL[64*64];   // rk band (8 KB), row 63 zero
  __shared__ __align__(16) ushort vTl[192*64];   // vT tile (24 KB)
  __shared__ __align__(16) ushort Pl[32][40];
  __shared__ __align__(16) float S1[32][34];     // pitch 34: 2-way write conflicts
  __shared__ __align__(16) float S2[32][66];
  __shared__ float corrl[32], linv[32];

  const int t = threadIdx.x;
  const int wv = t >> 6, lane = t & 63;
  const int lrow = lane & 15, lk8 = lane >> 4;
  const int bid = blockIdx.x;
  const int qt = bid % (TT/32);
  const int h  = (bid / (TT/32)) % HB;
  const int b  = bid / ((TT/32) * HB);
  const int q0 = qt * 32;

  // q A-fragments (loop-invariant, global->regs; carries 0.125*log2e via Wq tcast)
  bf16x8 af[2][2];
  #pragma unroll
  for (int rt = 0; rt < 2; ++rt)
    #pragma unroll
    for (int kh = 0; kh < 2; ++kh)
      af[rt][kh] = *(const bf16x8*)&qkv[((size_t)(b*TT) + q0 + rt*16 + lrow)*QKVP + h*KD + kh*32 + lk8*8];

  if (t < 32) ((uint*)rkbL)[63*32 + t] = 0;

  // ---- per-thread DMA pointers ----
  const int kc_r = t >> 3, kc_p = t & 7;
  const ushort* ksrc = qkv + (size_t)(b*TT + kc_r)*QKVP + 512 + h*KD + (kc_p ^ (kc_r & 7))*8;
  ushort* kdst = ktL + t*8;
  const int rr0 = t >> 3, rp0 = t & 7;
  const int rr1 = (256 + t) >> 3, rp1 = t & 7;
  const ushort* rsrc0 = rk + (size_t)(TT - 32 - q0 + rr0)*HK + h*KD + (rp0 ^ (rr0 & 7))*8;
  const ushort* rsrc1 = rk + (size_t)(TT - 32 - q0 + rr1)*HK + h*KD + (rp1 ^ (rr1 & 7))*8;
  ushort* rdst0 = rkbL + t*8;
  ushort* rdst1 = rkbL + (256 + t)*8;
  const bool rval = t < 248;
  const ushort* vsrc[6]; ushort* vdst[6];
  #pragma unroll
  for (int W = 0; W < 6; ++W) {
    const int c = W*256 + t;
    const int vd = c >> 3, cpk = c & 7;
    vsrc[W] = vTg + (size_t)(h*VD + vd)*(BT*TT) + b*TT + (cpk ^ (vd & 7))*8;
    vdst[W] = vTl + c*8;
  }

  // per-thread S columns
  const int jk  = (wv & 1)*16 + lrow;   // S1 col
  const int j2a = (wv & 1)*32 + lrow;   // S2 col (s2=0), <= 47
  const int j2b = j2a + 16;             // S2 col (s2=1), <= 63
  const int rt_ = wv >> 1;              // S-phase row tile

  f32x4 acc[2][3];
  #pragma unroll
  for (int i = 0; i < 2; ++i)
    #pragma unroll
    for (int j = 0; j < 3; ++j) acc[i][j] = (f32x4){0.f, 0.f, 0.f, 0.f};
  float m_i = -1e30f, l_i = 0.f;
  const int r_s = t >> 3;
  const int vsl = t & 7;

  // prologue: issue k/rkb for iter 0
  gload_lds16(ksrc, kdst);               ksrc += 32*QKVP;
  gload_lds16(rsrc0, rdst0);             rsrc0 += 32*HK;
  if (rval) gload_lds16(rsrc1, rdst1);
  rsrc1 += 32*HK;

  for (int it = 0; it < 48; ++it) {
    const int kt0 = it << 5;
    const int mbase = kt0 - q0 + (TT - 32);
    // c1/c2 register loads (branchless single loads per thread)
    const float c1v  = c1g[h*(BT*TT) + b*TT + kt0 + jk];
    const float c2v0 = c2g[(size_t)h*(2*TT - 1) + mbase + j2a];
    const float c2r  = c2g[(size_t)h*(2*TT - 1) + mbase + (j2b < 63 ? j2b : 62)];
    const float c2v1 = (j2b < 63) ? c2r : 0.f;

    if ((it & 1) == 0) {
      asm volatile("s_waitcnt lgkmcnt(0)" ::: "memory");
      __builtin_amdgcn_s_barrier();            // prev PV done reading vT
      #pragma unroll
      for (int W = 0; W < 6; ++W) { gload_lds16(vsrc[W], vdst[W]); vsrc[W] += 64; }
      asm volatile("s_waitcnt vmcnt(6)" ::: "memory");   // k/rkb retired; vT flies
      __builtin_amdgcn_s_barrier();
    } else {
      asm volatile("s_waitcnt vmcnt(3)" ::: "memory");   // k/rkb retired; c1c2 fly
      __builtin_amdgcn_s_barrier();
    }

    // ---- S-phase: S1 = q@k^T (+c1), S2 = q@rkb^T (+c2) ----
    {
      bf16x8 b0 = *(const bf16x8*)&ktL[jk*64 + ((lk8 ^ (jk & 7)) << 3)];
      bf16x8 b1 = *(const bf16x8*)&ktL[jk*64 + (((lk8 + 4) ^ (jk & 7)) << 3)];
      f32x4 c0 = (f32x4){0.f, 0.f, 0.f, 0.f};
      c0 = mfma_bf(af[rt_][0], b0, c0);
      c0 = mfma_bf(af[rt_][1], b1, c0);
      #pragma unroll
      for (int r = 0; r < 4; ++r) S1[rt_*16 + lk8*4 + r][jk] = c0[r] + c1v;

      bf16x8 d0 = *(const bf16x8*)&rkbL[j2a*64 + ((lk8 ^ (j2a & 7)) << 3)];
      bf16x8 d1 = *(const bf16x8*)&rkbL[j2a*64 + (((lk8 + 4) ^ (j2a & 7)) << 3)];
      f32x4 ca = (f32x4){0.f, 0.f, 0.f, 0.f};
      ca = mfma_bf(af[rt_][0], d0, ca);
      ca = mfma_bf(af[rt_][1], d1, ca);
      #pragma unroll
      for (int r = 0; r < 4; ++r) S2[rt_*16 + lk8*4 + r][j2a] = ca[r] + c2v0;

      bf16x8 e0 = *(const bf16x8*)&rkbL[j2b*64 + ((lk8 ^ (j2b & 7)) << 3)];
      bf16x8 e1 = *(const bf16x8*)&rkbL[j2b*64 + (((lk8 + 4) ^ (j2b & 7)) << 3)];
      f32x4 cb = (f32x4){0.f, 0.f, 0.f, 0.f};
      cb = mfma_bf(af[rt_][0], e0, cb);
      cb = mfma_bf(af[rt_][1], e1, cb);
      #pragma unroll
      for (int r = 0; r < 4; ++r) S2[rt_*16 + lk8*4 + r][j2b] = cb[r] + c2v1;
    }
    asm volatile("s_waitcnt lgkmcnt(0)" ::: "memory");
    __builtin_amdgcn_s_barrier();              // post-S: S visible; kt/rkb reads done
    if (it < 47) {                             // prefetch next k/rkb (overlaps softmax+PV)
      gload_lds16(ksrc, kdst);               ksrc += 32*QKVP;
      gload_lds16(rsrc0, rdst0);             rsrc0 += 32*HK;
      if (rval) gload_lds16(rsrc1, rdst1);
      rsrc1 += 32*HK;
    }
    // ---- online softmax (exp2 domain, defer-max THR=8) ----
    {
      float sv[4];
      #pragma unroll
      for (int i = 0; i < 4; ++i) {
        const int j = vsl*4 + i;
        sv[i] = S1[r_s][j] + S2[r_s][j - r_s + 31];
      }
      float lmax = fmaxf(fmaxf(sv[0], sv[1]), fmaxf(sv[2], sv[3]));
      #pragma unroll
      for (int s = 1; s < 8; s <<= 1) lmax = fmaxf(lmax, __shfl_xor(lmax, s, 64));
      const bool defer = (lmax <= m_i + 8.0f);
      const float m_new = defer ? m_i : fmaxf(m_i, lmax);
      const float corr  = defer ? 1.0f : exp2f(m_i - m_new);
      const float p0 = exp2f(sv[0] - m_new), p1 = exp2f(sv[1] - m_new);
      const float p2 = exp2f(sv[2] - m_new), p3 = exp2f(sv[3] - m_new);
      uint2v pw;
      pw.x = (uint)f2bf(p0) | ((uint)f2bf(p1) << 16);
      pw.y = (uint)f2bf(p2) | ((uint)f2bf(p3) << 16);
      *(uint2v*)&Pl[r_s][vsl*4] = pw;
      float lsum = (p0 + p1) + (p2 + p3);
      #pragma unroll
      for (int s = 1; s < 8; s <<= 1) lsum += __shfl_xor(lsum, s, 64);
      l_i = l_i * corr + lsum;
      m_i = m_new;
      if (vsl == 0) corrl[r_s] = corr;
    }
    if ((it & 1) == 0) { asm volatile("s_waitcnt vmcnt(3)" ::: "memory"); }  // vT drained
    asm volatile("s_waitcnt lgkmcnt(0)" ::: "memory");
    __builtin_amdgcn_s_barrier();              // post-softmax
    // ---- PV (rescale skipped when all corr==1) ----
    {
      const int kh4 = (it & 1) * 4;
      float cr[2][4];
      #pragma unroll
      for (int rt = 0; rt < 2; ++rt)
        #pragma unroll
        for (int r = 0; r < 4; ++r) cr[rt][r] = corrl[rt*16 + lk8*4 + r];
      bool need = false;
      #pragma unroll
      for (int rt = 0; rt < 2; ++rt)
        #pragma unroll
        for (int r = 0; r < 4; ++r) need |= (cr[rt][r] != 1.0f);
      if (__any(need ? 1 : 0)) {
        #pragma unroll
        for (int rt = 0; rt < 2; ++rt)
          #pragma unroll
          for (int cc = 0; cc < 3; ++cc)
            #pragma unroll
            for (int r = 0; r < 4; ++r) acc[rt][cc][r] *= cr[rt][r];
      }
      #pragma unroll
      for (int rt = 0; rt < 2; ++rt) {
        const bf16x8 pa = *(const bf16x8*)&Pl[rt*16 + lrow][lk8*8];
        #pragma unroll
        for (int cc = 0; cc < 3; ++cc) {
          const int rv = (3*wv + cc)*16 + lrow;
          const bf16x8 bv = *(const bf16x8*)&vTl[rv*64 + (((kh4 + lk8) ^ (rv & 7)) << 3)];
          acc[rt][cc] = mfma_bf(pa, bv, acc[rt][cc]);
        }
      }
    }
  }
  if (vsl == 0) linv[r_s] = 1.0f / l_i;
  __syncthreads();
  #pragma unroll
  for (int rt = 0; rt < 2; ++rt) {
    #pragma unroll
    for (int cc = 0; cc < 3; ++cc) {
      const int colg = (3*wv + cc)*16 + lrow;
      #pragma unroll
      for (int r = 0; r < 4; ++r) {
        const int rowg = rt*16 + lk8*4 + r;
        aout[((size_t)(b*TT) + q0 + rowg) * HV + h*VD + colg] = f2bf(acc[rt][cc][r] * linv[rowg]);
      }
    }
  }
}

extern "C" void kernel_launch(void* const* d_in, const int* in_sizes, int n_in,
                              void* d_out, int out_size, void* d_ws, size_t ws_size,
                              hipStream_t stream)
{
  const float* X   = (const float*)d_in[0];
  const float* Wq  = (const float*)d_in[1];
  const float* Wk  = (const float*)d_in[2];
  const float* Wv  = (const float*)d_in[3];
  const float* Wrk = (const float*)d_in[4];
  const float* We  = (const float*)d_in[5];
  const float* be  = (const float*)d_in[6];
  const float* rwb = (const float*)d_in[7];
  const float* rrb = (const float*)d_in[8];
  float* out = (float*)d_out;

  char* ws = (char*)d_ws;
  ushort* Xb    = (ushort*)ws;                       ws += (size_t)3072*1536*2;
  ushort* Wqkvt = (ushort*)ws;                       ws += (size_t)2560*1536*2;
  ushort* Wet   = (ushort*)ws;                       ws += (size_t)1536*1536*2;
  float*  S1b   = (float*)ws;                        ws += (size_t)97*512*4;
  float*  S2b   = (float*)ws;                        ws += (size_t)97*512*4;
  ushort* qkvb  = (ushort*)ws;                       ws += (size_t)3072*2560*2;
  ushort* vTgb  = (ushort*)ws;                       ws += (size_t)1536*3072*2;
  ushort* rkb   = (ushort*)ws;                       ws += (size_t)3071*512*2;
  float*  c1g   = (float*)ws;                        ws += (size_t)8*3072*4;
  float*  c2g   = (float*)ws;                        ws += (size_t)8*3071*4;
  ushort* ao    = (ushort*)ws;                       // 3072*1536*2

  dim3 blk(256);
  cast_bf16<<<2048, blk, 0, stream>>>(X, Xb, (3072*1536)/4);
  tcast<<<dim3(512/32, 1536/32),  dim3(32,8), 0, stream>>>(Wq, Wqkvt,                      1536, 512,  0.125f*LOG2E);
  tcast<<<dim3(512/32, 1536/32),  dim3(32,8), 0, stream>>>(Wk, Wqkvt + (size_t)512*1536,   1536, 512,  1.0f);
  tcast<<<dim3(1536/32, 1536/32), dim3(32,8), 0, stream>>>(Wv, Wqkvt + (size_t)1024*1536,  1536, 1536, 1.0f);
  tcast<<<dim3(1536/32, 1536/32), dim3(32,8), 0, stream>>>(We, Wet, 1536, 1536, 1.0f);
  wrk_suffix<<<2, blk, 0, stream>>>(Wrk, S1b, S2b);
  relk_fill<<<dim3(2*TT - 1), blk, 0, stream>>>(S1b, S2b, rrb, rkb, c2g);
  gemm_bf16<false, ushort><<<dim3(20, 24), blk, 0, stream>>>(Xb, Wqkvt, nullptr, qkvb, 3072, QKVP, 1536);
  vtrans<<<dim3(1536/32, 3072/32), dim3(32,8), 0, stream>>>(qkvb, vTgb);
  c1_kernel<<<96, blk, 0, stream>>>(qkvb, rwb, c1g);
  attn_mfma<<<dim3(BT*HB*(TT/32)), blk, 0, stream>>>(qkvb, vTgb, rkb, c1g, c2g, ao);
  gemm_bf16<true, float><<<dim3(12, 24), blk, 0, stream>>>(ao, Wet, be, out, 3072, 1536, 1536);
}

// Round 8
// 217.915 us; speedup vs baseline: 9.2323x; 1.0285x over previous
//
#include <hip/hip_runtime.h>
#include <math.h>

#define HB 8
#define KD 64
#define VD 192
#define BT 2
#define TT 1536
#define CC 1536
#define HK (HB*KD)   // 512
#define HV (HB*VD)   // 1536
#define QKVP 2560    // fused qkv row pitch: q[0:512) k[512:1024) v[1024:2560)
#define LOG2E 1.44269504088896340736f

typedef float f32x4 __attribute__((ext_vector_type(4)));
typedef __bf16 bf16x8 __attribute__((ext_vector_type(8)));

static __device__ __forceinline__ ushort f2bf(float f) {
  union { float f; uint u; } v; v.f = f;
  uint r = (v.u + 0x7FFFu + ((v.u >> 16) & 1u)) >> 16;  // RNE
  return (ushort)r;
}
static __device__ __forceinline__ float bf2f(ushort u) {
  union { uint u; float f; } v; v.u = ((uint)u) << 16; return v.f;
}

static __device__ __forceinline__ f32x4 mfma_bf(bf16x8 a, bf16x8 b, f32x4 c) {
  return __builtin_amdgcn_mfma_f32_16x16x32_bf16(a, b, c, 0, 0, 0);
}

static __device__ __forceinline__ void gload_lds16(const ushort* g, ushort* l) {
  __builtin_amdgcn_global_load_lds(
      (const __attribute__((address_space(1))) unsigned int*)g,
      (__attribute__((address_space(3))) unsigned int*)l, 16, 0, 0);
}

__device__ __forceinline__ void storeC(float* p, float v) { *p = v; }
__device__ __forceinline__ void storeC(ushort* p, float v) { *p = f2bf(v); }

// ---------------- cast fp32 -> bf16 (vectorized) ----------------
__global__ __launch_bounds__(256) void cast_bf16(
    const float* __restrict__ in, ushort* __restrict__ out, int n4)
{
  for (int i = blockIdx.x*blockDim.x + threadIdx.x; i < n4; i += gridDim.x*blockDim.x) {
    float4 v = ((const float4*)in)[i];
    ushort4 o; o.x = f2bf(v.x); o.y = f2bf(v.y); o.z = f2bf(v.z); o.w = f2bf(v.w);
    ((ushort4*)out)[i] = o;
  }
}

// ---------------- transpose + cast + scale: in[R][C] fp32 -> out[C][R] bf16 ----------------
__global__ void tcast(const float* __restrict__ in, ushort* __restrict__ out, int R, int C, float scale)
{
  __shared__ float tile[32][33];
  const int bx = blockIdx.x * 32;
  const int by = blockIdx.y * 32;
  const int tx = threadIdx.x, ty = threadIdx.y;  // (32,8)
  #pragma unroll
  for (int i = 0; i < 4; ++i)
    tile[ty + i*8][tx] = in[(size_t)(by + ty + i*8)*C + bx + tx];
  __syncthreads();
  #pragma unroll
  for (int i = 0; i < 4; ++i)
    out[(size_t)(bx + ty + i*8)*R + by + tx] = f2bf(tile[tx][ty + i*8] * scale);
}

// ---------------- bf16 transpose of V section: qkv[key][1024+vd] -> vTg[vd][key] ----------------
__global__ void vtrans(const ushort* __restrict__ in, ushort* __restrict__ out)
{
  __shared__ ushort tile[32][33];
  const int bx = blockIdx.x * 32;  // vd base
  const int by = blockIdx.y * 32;  // key base
  const int tx = threadIdx.x, ty = threadIdx.y;  // (32,8)
  #pragma unroll
  for (int i = 0; i < 4; ++i)
    tile[ty + i*8][tx] = in[(size_t)(by + ty + i*8)*QKVP + 1024 + bx + tx];
  __syncthreads();
  #pragma unroll
  for (int i = 0; i < 4; ++i)
    out[(size_t)(bx + ty + i*8)*(BT*TT) + by + tx] = tile[tx][ty + i*8];
}

// ---------------- bf16 MFMA GEMM: C[M,N] = A[M,Kd] @ Bt[N,Kd]^T (+bias) ----------------
template<bool WITH_BIAS, typename OutT>
__global__ __launch_bounds__(256) void gemm_bf16(
    const ushort* __restrict__ A, const ushort* __restrict__ Bt,
    const float* __restrict__ bias, OutT* __restrict__ C,
    int M, int N, int Kd)
{
  __shared__ __align__(16) ushort As[128*64];
  __shared__ __align__(16) ushort Bs[128*64];
  const int t = threadIdx.x;
  const int w = t >> 6, lane = t & 63;
  const int lrow = lane & 15, lk8 = lane >> 4;
  const int row0 = blockIdx.y * 128, col0 = blockIdx.x * 128;
  const int wr = (w >> 1) * 64, wc = (w & 1) * 64;

  f32x4 acc[4][4];
  #pragma unroll
  for (int m = 0; m < 4; ++m)
    #pragma unroll
    for (int n = 0; n < 4; ++n) acc[m][n] = (f32x4){0.f,0.f,0.f,0.f};

  for (int k0 = 0; k0 < Kd; k0 += 64) {
    __syncthreads();
    #pragma unroll
    for (int j = 0; j < 4; ++j) {
      const int c = (w*4 + j)*64 + lane;
      const int r = c >> 3, cp = c & 7;
      const int sc = cp ^ (r & 7);
      gload_lds16(A  + (size_t)(row0 + r)*Kd + k0 + sc*8, As + c*8);
      gload_lds16(Bt + (size_t)(col0 + r)*Kd + k0 + sc*8, Bs + c*8);
    }
    __syncthreads();
    bf16x8 af[4][2], bfv[4][2];
    #pragma unroll
    for (int m = 0; m < 4; ++m) {
      const int r = wr + m*16 + lrow;
      #pragma unroll
      for (int kh = 0; kh < 2; ++kh) {
        const int k8 = lk8 + kh*4;
        af[m][kh] = *(const bf16x8*)&As[r*64 + ((k8 ^ (r & 7)) << 3)];
      }
    }
    #pragma unroll
    for (int n = 0; n < 4; ++n) {
      const int r = wc + n*16 + lrow;
      #pragma unroll
      for (int kh = 0; kh < 2; ++kh) {
        const int k8 = lk8 + kh*4;
        bfv[n][kh] = *(const bf16x8*)&Bs[r*64 + ((k8 ^ (r & 7)) << 3)];
      }
    }
    #pragma unroll
    for (int m = 0; m < 4; ++m)
      #pragma unroll
      for (int n = 0; n < 4; ++n) {
        acc[m][n] = mfma_bf(af[m][0], bfv[n][0], acc[m][n]);
        acc[m][n] = mfma_bf(af[m][1], bfv[n][1], acc[m][n]);
      }
  }
  #pragma unroll
  for (int m = 0; m < 4; ++m)
    #pragma unroll
    for (int n = 0; n < 4; ++n) {
      const int cg = col0 + wc + n*16 + lrow;
      const float bb = WITH_BIAS ? bias[cg] : 0.f;
      #pragma unroll
      for (int r = 0; r < 4; ++r) {
        const int rg = row0 + wr + m*16 + lk8*4 + r;
        storeC(&C[(size_t)rg*N + cg], acc[m][n][r] + bb);
      }
    }
}

// ---------------- Wrk suffix sums ----------------
__global__ __launch_bounds__(256) void wrk_suffix(
    const float* __restrict__ Wrk, float* __restrict__ S1, float* __restrict__ S2)
{
  const int c = blockIdx.x*blockDim.x + threadIdx.x;
  float a1 = 0.f, a2 = 0.f;
  S1[96*HK + c] = 0.f; S2[96*HK + c] = 0.f;
  for (int i = 95; i >= 0; --i) {
    a1 += Wrk[i*HK + c];
    a2 += Wrk[(96 + i)*HK + c];
    S1[i*HK + c] = a1; S2[i*HK + c] = a2;
  }
}

// ---------------- rk[m][c] bf16 + c2[h][m] = (rrb_h . rk[m]) * log2e ----------------
__global__ __launch_bounds__(256) void relk_fill(
    const float* __restrict__ S1, const float* __restrict__ S2,
    const float* __restrict__ rrb, ushort* __restrict__ rk, float* __restrict__ c2g)
{
  __shared__ float cw[96];
  __shared__ float red[512];
  __shared__ int i0s;
  const int t = threadIdx.x;
  const int m = blockIdx.x;            // 0 .. 2T-2
  if (t < 96) {
    double pr = exp(log((double)(TT + 1)) / 96.0);
    float prf = (float)pr;
    cw[t] = (float)pow((double)prf, (double)(t + 1)) - 1.0f;
  }
  __syncthreads();
  const int d = m - (TT - 1);
  const float ad = fabsf((float)d);
  if (t == 0) {
    int i0 = 96;
    for (int i = 0; i < 96; ++i) if (cw[i] > ad) { i0 = i; break; }
    i0s = i0;
  }
  __syncthreads();
  const float sg = (d > 0) ? 1.f : (d < 0 ? -1.f : 0.f);
  const int i0 = i0s;
  for (int c = t; c < HK; c += 256) {
    const float val = S1[i0*HK + c] + sg * S2[i0*HK + c];
    const ushort vb = f2bf(val);
    rk[(size_t)m * HK + c] = vb;
    red[c] = bf2f(vb) * rrb[c];
  }
  __syncthreads();
  if (t < 8) {
    float s = 0.f;
    #pragma unroll 16
    for (int i = 0; i < 64; ++i) s += red[t*64 + i];
    c2g[(size_t)t*(2*TT - 1) + m] = s * LOG2E;
  }
}

// ---------------- c1[h][row] = (rwb_h . k[row]) * log2e ----------------
__global__ __launch_bounds__(256) void c1_kernel(
    const ushort* __restrict__ qkv, const float* __restrict__ rwb, float* __restrict__ c1g)
{
  const int idx = blockIdx.x*256 + threadIdx.x;  // 3072*8
  const int h = idx & 7, row = idx >> 3;
  const ushort* kr = &qkv[(size_t)row*QKVP + 512 + h*KD];
  float s = 0.f;
  #pragma unroll 16
  for (int c = 0; c < 64; ++c) s += bf2f(kr[c]) * rwb[h*KD + c];
  c1g[h*(BT*TT) + row] = s * LOG2E;
}

// ---------------- fused relative attention: KBLK=64, counted-vmcnt DMA pipeline ----------------
__global__ __launch_bounds__(256, 2) void attn_mfma(
    const ushort* __restrict__ qkv, const ushort* __restrict__ vTg,
    const ushort* __restrict__ rk,
    const float* __restrict__ c1g, const float* __restrict__ c2g,
    ushort* __restrict__ aout)
{
  __shared__ __align__(16) ushort ktL[64*64];    // k tile (8 KB)
  __shared__ __align__(16) ushort rkbL[96*64];   // rk band (12 KB), row 95 zero
  __shared__ __align__(16) ushort vTl[192*64];   // vT tile (24 KB)
  __shared__ __align__(16) ushort Pl[32][72];    // probabilities bf16 (4.5 KB)
  __shared__ __align__(16) float S1[32][68];     // content logits (8.5 KB)
  __shared__ __align__(16) float S2[32][98];     // rel logits, 95-wide band (12.25 KB)
  __shared__ float corrl[32], linv[32];

  const int t = threadIdx.x;
  const int wv = t >> 6, lane = t & 63;
  const int lrow = lane & 15, lk8 = lane >> 4;
  const int bid = blockIdx.x;
  const int qt = bid % (TT/32);
  const int h  = (bid / (TT/32)) % HB;
  const int b  = bid / ((TT/32) * HB);
  const int q0 = qt * 32;

  // q A-fragments (loop-invariant; named regs so rt-select is cndmask, not scratch)
  bf16x8 af00, af01, af10, af11;
  {
    const ushort* qbase = &qkv[((size_t)(b*TT) + q0 + lrow)*QKVP + h*KD];
    af00 = *(const bf16x8*)&qbase[lk8*8];
    af01 = *(const bf16x8*)&qbase[32 + lk8*8];
    af10 = *(const bf16x8*)&qbase[16*QKVP + lk8*8];
    af11 = *(const bf16x8*)&qbase[16*QKVP + 32 + lk8*8];
  }

  if (t < 32) ((uint*)rkbL)[95*32 + t] = 0;   // zero pad row 95

  // ---- per-thread DMA pointers ----
  const ushort* ksrc[2]; ushort* kdst[2];
  #pragma unroll
  for (int W = 0; W < 2; ++W) {
    const int c = W*256 + t;
    const int r = c >> 3, cp = c & 7;
    ksrc[W] = qkv + (size_t)(b*TT + r)*QKVP + 512 + h*KD + (cp ^ (r & 7))*8;
    kdst[W] = ktL + c*8;
  }
  const ushort* rsrc[3]; ushort* rdst[3];
  #pragma unroll
  for (int W = 0; W < 3; ++W) {
    const int c = W*256 + t;
    const int r = c >> 3, cp = c & 7;
    rsrc[W] = rk + (size_t)(1504 - q0 + r)*HK + h*KD + (cp ^ (r & 7))*8;
    rdst[W] = rkbL + c*8;
  }
  const bool rval = t < 248;   // round-2 validity (band row < 95)
  const ushort* vsrc[6]; ushort* vdst[6];
  #pragma unroll
  for (int W = 0; W < 6; ++W) {
    const int c = W*256 + t;
    const int vd = c >> 3, cpk = c & 7;
    vsrc[W] = vTg + (size_t)(h*VD + vd)*(BT*TT) + b*TT + (cpk ^ (vd & 7))*8;
    vdst[W] = vTl + c*8;
  }

  // per-thread S tile columns (loop-invariant)
  int jk_[2], rt1_[2], j2_[3], rt2_[3];
  #pragma unroll
  for (int s = 0; s < 2; ++s) {
    const int idx = wv*2 + s;
    rt1_[s] = idx >> 2; jk_[s] = (idx & 3)*16 + lrow;
  }
  #pragma unroll
  for (int s = 0; s < 3; ++s) {
    const int idx = wv*3 + s;
    rt2_[s] = (idx >= 6) ? 1 : 0; j2_[s] = (idx - 6*rt2_[s])*16 + lrow;
  }

  f32x4 acc[2][3];
  #pragma unroll
  for (int i = 0; i < 2; ++i)
    #pragma unroll
    for (int j = 0; j < 3; ++j) acc[i][j] = (f32x4){0.f, 0.f, 0.f, 0.f};
  float m_i = -1e30f, l_i = 0.f;
  const int r_s = t >> 3;
  const int vsl = t & 7;

  // ---- prologue: prefetch c1/c2(it0), issue k/rkb + vT for it0 ----
  float c1p[2], c2p[3];
  {
    const int mb0 = -q0 + 1504;
    #pragma unroll
    for (int s = 0; s < 2; ++s) c1p[s] = c1g[h*(BT*TT) + b*TT + jk_[s]];
    #pragma unroll
    for (int s = 0; s < 3; ++s) {
      const float v = c2g[(size_t)h*(2*TT - 1) + mb0 + (j2_[s] < 95 ? j2_[s] : 94)];
      c2p[s] = (j2_[s] < 95) ? v : 0.f;
    }
  }
  #pragma unroll
  for (int W = 0; W < 2; ++W) { gload_lds16(ksrc[W], kdst[W]); ksrc[W] += 64*QKVP; }
  gload_lds16(rsrc[0], rdst[0]);           rsrc[0] += 64*HK;
  gload_lds16(rsrc[1], rdst[1]);           rsrc[1] += 64*HK;
  if (rval) gload_lds16(rsrc[2], rdst[2]);
  rsrc[2] += 64*HK;
  #pragma unroll
  for (int W = 0; W < 6; ++W) { gload_lds16(vsrc[W], vdst[W]); vsrc[W] += 64; }

  for (int it = 0; it < 24; ++it) {
    // ==== phase A: S-compute (k/rkb + c1c2 retired; vT still flying) ====
    asm volatile("s_waitcnt vmcnt(6)" ::: "memory");
    __builtin_amdgcn_s_barrier();
    #pragma unroll
    for (int s = 0; s < 2; ++s) {
      const int rt = rt1_[s], jk = jk_[s];
      const bf16x8 a0 = rt ? af10 : af00;
      const bf16x8 a1 = rt ? af11 : af01;
      bf16x8 b0 = *(const bf16x8*)&ktL[jk*64 + ((lk8 ^ (jk & 7)) << 3)];
      bf16x8 b1 = *(const bf16x8*)&ktL[jk*64 + (((lk8 + 4) ^ (jk & 7)) << 3)];
      f32x4 c0 = (f32x4){0.f, 0.f, 0.f, 0.f};
      c0 = mfma_bf(a0, b0, c0);
      c0 = mfma_bf(a1, b1, c0);
      #pragma unroll
      for (int r = 0; r < 4; ++r) S1[rt*16 + lk8*4 + r][jk] = c0[r] + c1p[s];
    }
    #pragma unroll
    for (int s = 0; s < 3; ++s) {
      const int rt = rt2_[s], j2 = j2_[s];
      const bf16x8 a0 = rt ? af10 : af00;
      const bf16x8 a1 = rt ? af11 : af01;
      bf16x8 b0 = *(const bf16x8*)&rkbL[j2*64 + ((lk8 ^ (j2 & 7)) << 3)];
      bf16x8 b1 = *(const bf16x8*)&rkbL[j2*64 + (((lk8 + 4) ^ (j2 & 7)) << 3)];
      f32x4 c0 = (f32x4){0.f, 0.f, 0.f, 0.f};
      c0 = mfma_bf(a0, b0, c0);
      c0 = mfma_bf(a1, b1, c0);
      #pragma unroll
      for (int r = 0; r < 4; ++r) S2[rt*16 + lk8*4 + r][j2] = c0[r] + c2p[s];
    }
    asm volatile("s_waitcnt lgkmcnt(0)" ::: "memory");
    __builtin_amdgcn_s_barrier();

    // ==== phase B: issue next k/rkb + c1c2 prefetch; softmax; retire vT ====
    if (it < 23) {
      #pragma unroll
      for (int W = 0; W < 2; ++W) { gload_lds16(ksrc[W], kdst[W]); ksrc[W] += 64*QKVP; }
      gload_lds16(rsrc[0], rdst[0]);           rsrc[0] += 64*HK;
      gload_lds16(rsrc[1], rdst[1]);           rsrc[1] += 64*HK;
      if (rval) gload_lds16(rsrc[2], rdst[2]);
      rsrc[2] += 64*HK;
      const int kt0n = (it + 1) << 6;
      const int mbn = kt0n - q0 + 1504;
      #pragma unroll
      for (int s = 0; s < 2; ++s) c1p[s] = c1g[h*(BT*TT) + b*TT + kt0n + jk_[s]];
      #pragma unroll
      for (int s = 0; s < 3; ++s) {
        const float v = c2g[(size_t)h*(2*TT - 1) + mbn + (j2_[s] < 95 ? j2_[s] : 94)];
        c2p[s] = (j2_[s] < 95) ? v : 0.f;
      }
    }
    {
      float sv[8];
      #pragma unroll
      for (int i = 0; i < 8; ++i) {
        const int j = vsl*8 + i;
        sv[i] = S1[r_s][j] + S2[r_s][j - r_s + 31];
      }
      float lmax = sv[0];
      #pragma unroll
      for (int i = 1; i < 8; ++i) lmax = fmaxf(lmax, sv[i]);
      #pragma unroll
      for (int s = 1; s < 8; s <<= 1) lmax = fmaxf(lmax, __shfl_xor(lmax, s, 64));
      const bool defer = (lmax <= m_i + 8.0f);
      const float m_new = defer ? m_i : fmaxf(m_i, lmax);
      const float corr  = defer ? 1.0f : exp2f(m_i - m_new);
      float p[8];
      float lsum = 0.f;
      #pragma unroll
      for (int i = 0; i < 8; ++i) { p[i] = exp2f(sv[i] - m_new); lsum += p[i]; }
      uint4 pw;
      pw.x = (uint)f2bf(p[0]) | ((uint)f2bf(p[1]) << 16);
      pw.y = (uint)f2bf(p[2]) | ((uint)f2bf(p[3]) << 16);
      pw.z = (uint)f2bf(p[4]) | ((uint)f2bf(p[5]) << 16);
      pw.w = (uint)f2bf(p[6]) | ((uint)f2bf(p[7]) << 16);
      *(uint4*)&Pl[r_s][vsl*8] = pw;
      #pragma unroll
      for (int s = 1; s < 8; s <<= 1) lsum += __shfl_xor(lsum, s, 64);
      l_i = l_i * corr + lsum;
      m_i = m_new;
      if (vsl == 0) corrl[r_s] = corr;
    }
    if (it < 23) { asm volatile("s_waitcnt vmcnt(10)" ::: "memory"); }
    else         { asm volatile("s_waitcnt vmcnt(0)"  ::: "memory"); }
    asm volatile("s_waitcnt lgkmcnt(0)" ::: "memory");
    __builtin_amdgcn_s_barrier();

    // ==== phase C: PV (operands -> regs, barrier, issue next vT, MFMA) ====
    {
      bf16x8 pa[2][2], bv[3][2];
      #pragma unroll
      for (int rt = 0; rt < 2; ++rt) {
        pa[rt][0] = *(const bf16x8*)&Pl[rt*16 + lrow][lk8*8];
        pa[rt][1] = *(const bf16x8*)&Pl[rt*16 + lrow][32 + lk8*8];
      }
      #pragma unroll
      for (int cc = 0; cc < 3; ++cc) {
        const int rv = (3*wv + cc)*16 + lrow;
        bv[cc][0] = *(const bf16x8*)&vTl[rv*64 + ((lk8 ^ (rv & 7)) << 3)];
        bv[cc][1] = *(const bf16x8*)&vTl[rv*64 + (((lk8 + 4) ^ (rv & 7)) << 3)];
      }
      float cr[2][4];
      #pragma unroll
      for (int rt = 0; rt < 2; ++rt)
        #pragma unroll
        for (int r = 0; r < 4; ++r) cr[rt][r] = corrl[rt*16 + lk8*4 + r];
      asm volatile("s_waitcnt lgkmcnt(0)" ::: "memory");
      __builtin_amdgcn_s_barrier();
      if (it < 23) {
        #pragma unroll
        for (int W = 0; W < 6; ++W) { gload_lds16(vsrc[W], vdst[W]); vsrc[W] += 64; }
      }
      bool need = false;
      #pragma unroll
      for (int rt = 0; rt < 2; ++rt)
        #pragma unroll
        for (int r = 0; r < 4; ++r) need |= (cr[rt][r] != 1.0f);
      if (__any(need ? 1 : 0)) {
        #pragma unroll
        for (int rt = 0; rt < 2; ++rt)
          #pragma unroll
          for (int cc = 0; cc < 3; ++cc)
            #pragma unroll
            for (int r = 0; r < 4; ++r) acc[rt][cc][r] *= cr[rt][r];
      }
      #pragma unroll
      for (int rt = 0; rt < 2; ++rt)
        #pragma unroll
        for (int cc = 0; cc < 3; ++cc) {
          acc[rt][cc] = mfma_bf(pa[rt][0], bv[cc][0], acc[rt][cc]);
          acc[rt][cc] = mfma_bf(pa[rt][1], bv[cc][1], acc[rt][cc]);
        }
    }
  }
  if (vsl == 0) linv[r_s] = 1.0f / l_i;
  __syncthreads();
  #pragma unroll
  for (int rt = 0; rt < 2; ++rt) {
    #pragma unroll
    for (int cc = 0; cc < 3; ++cc) {
      const int colg = (3*wv + cc)*16 + lrow;
      #pragma unroll
      for (int r = 0; r < 4; ++r) {
        const int rowg = rt*16 + lk8*4 + r;
        aout[((size_t)(b*TT) + q0 + rowg) * HV + h*VD + colg] = f2bf(acc[rt][cc][r] * linv[rowg]);
      }
    }
  }
}

extern "C" void kernel_launch(void* const* d_in, const int* in_sizes, int n_in,
                              void* d_out, int out_size, void* d_ws, size_t ws_size,
                              hipStream_t stream)
{
  const float* X   = (const float*)d_in[0];
  const float* Wq  = (const float*)d_in[1];
  const float* Wk  = (const float*)d_in[2];
  const float* Wv  = (const float*)d_in[3];
  const float* Wrk = (const float*)d_in[4];
  const float* We  = (const float*)d_in[5];
  const float* be  = (const float*)d_in[6];
  const float* rwb = (const float*)d_in[7];
  const float* rrb = (const float*)d_in[8];
  float* out = (float*)d_out;

  char* ws = (char*)d_ws;
  ushort* Xb    = (ushort*)ws;                       ws += (size_t)3072*1536*2;
  ushort* Wqkvt = (ushort*)ws;                       ws += (size_t)2560*1536*2;
  ushort* Wet   = (ushort*)ws;                       ws += (size_t)1536*1536*2;
  float*  S1b   = (float*)ws;                        ws += (size_t)97*512*4;
  float*  S2b   = (float*)ws;                        ws += (size_t)97*512*4;
  ushort* qkvb  = (ushort*)ws;                       ws += (size_t)3072*2560*2;
  ushort* vTgb  = (ushort*)ws;                       ws += (size_t)1536*3072*2;
  ushort* rkb   = (ushort*)ws;                       ws += (size_t)3071*512*2;
  float*  c1g   = (float*)ws;                        ws += (size_t)8*3072*4;
  float*  c2g   = (float*)ws;                        ws += (size_t)8*3071*4;
  ushort* ao    = (ushort*)ws;                       // 3072*1536*2

  dim3 blk(256);
  cast_bf16<<<2048, blk, 0, stream>>>(X, Xb, (3072*1536)/4);
  tcast<<<dim3(512/32, 1536/32),  dim3(32,8), 0, stream>>>(Wq, Wqkvt,                      1536, 512,  0.125f*LOG2E);
  tcast<<<dim3(512/32, 1536/32),  dim3(32,8), 0, stream>>>(Wk, Wqkvt + (size_t)512*1536,   1536, 512,  1.0f);
  tcast<<<dim3(1536/32, 1536/32), dim3(32,8), 0, stream>>>(Wv, Wqkvt + (size_t)1024*1536,  1536, 1536, 1.0f);
  tcast<<<dim3(1536/32, 1536/32), dim3(32,8), 0, stream>>>(We, Wet, 1536, 1536, 1.0f);
  wrk_suffix<<<2, blk, 0, stream>>>(Wrk, S1b, S2b);
  relk_fill<<<dim3(2*TT - 1), blk, 0, stream>>>(S1b, S2b, rrb, rkb, c2g);
  gemm_bf16<false, ushort><<<dim3(20, 24), blk, 0, stream>>>(Xb, Wqkvt, nullptr, qkvb, 3072, QKVP, 1536);
  vtrans<<<dim3(1536/32, 3072/32), dim3(32,8), 0, stream>>>(qkvb, vTgb);
  c1_kernel<<<96, blk, 0, stream>>>(qkvb, rwb, c1g);
  attn_mfma<<<dim3(BT*HB*(TT/32)), blk, 0, stream>>>(qkvb, vTgb, rkb, c1g, c2g, ao);
  gemm_bf16<true, float><<<dim3(12, 24), blk, 0, stream>>>(ao, Wet, be, out, 3072, 1536, 1536);
}